// Round 6
// baseline (441.476 us; speedup 1.0000x reference)
//
#include <hip/hip_runtime.h>
#include <hip/hip_bf16.h>

// ---------------------------------------------------------------------------
// CrossAttentionBlock: bilinear 3x upsample -> QKV 1x1 projections ->
// full cross-attention (N=9216, E=64, Co=32) -> 1x1 conv + BN + ReLU.
// Flash-style, fp16 MFMA 16x16x32, fp32 accumulate, no-max softmax
// (scores bounded), split-m partials combined additively in epilogue.
//
// R6 changes vs R5 (225us attn, 118MB FETCH / 175MB WRITE amplification):
//  - attn: block = 4 waves = one 32-row group x 4-way m-split of a SPLIT=8
//    chunk; pairwise LDS combine (8KB); ONE f32x4-store write per block ->
//    OutWS stays 18.9MB (R1/R4-proven no write amplification) while wave
//    count grows to 18432 (18/SIMD supply vs R5's 9).
//  - proj_q / proj_kv: e-quarter split -> 4x waves (288 blocks each).
// ---------------------------------------------------------------------------

constexpr int B   = 2;
constexpr int N   = 9216;   // 96*96
constexpr int E   = 64;
constexpr int CO  = 32;
constexpr int CT  = 64;
constexpr int SPLIT  = 8;
constexpr int MCHUNK = N / SPLIT;     // 1152
constexpr int MSUB   = MCHUNK / 4;    // 288 per wave

typedef _Float16 f16x8 __attribute__((ext_vector_type(8)));
typedef _Float16 f16x4 __attribute__((ext_vector_type(4)));
typedef float    f32x4 __attribute__((ext_vector_type(4)));

#define MFMA(a, b, c) __builtin_amdgcn_mfma_f32_16x16x32_f16((a), (b), (c), 0, 0, 0)

// exp(s/8) == exp2(s * SC); SC folded into Q projection weights.
#define SC 0.18033688011112042f

// ---------------------------------------------------------------------------
// Kernel 1: bilinear upsample (half-pixel, clamped) + Q projection.
// Thread handles (pixel, e-quarter): lanes 4*p..4*p+3 share a pixel.
// Q stored [B][N][E] fp16, PRE-SCALED by SC.
// ---------------------------------------------------------------------------
__global__ __launch_bounds__(256) void proj_q_kernel(
    const float* __restrict__ xt,   // [B][64][32][32]
    const float* __restrict__ qw,   // [64][64]
    const float* __restrict__ qb,   // [64]
    _Float16* __restrict__ Q)
{
  const int tid = blockIdx.x * 256 + threadIdx.x;
  const int p   = tid >> 2;          // 0..18431
  const int eq  = tid & 3;           // e-quarter
  const int b   = p / N, n = p % N;
  const int ho  = n / 96, wo = n % 96;

  const float sh = (ho + 0.5f) * (1.0f / 3.0f) - 0.5f;
  const float sw = (wo + 0.5f) * (1.0f / 3.0f) - 0.5f;
  int h0 = (int)floorf(sh); const float fh = sh - (float)h0;
  int w0 = (int)floorf(sw); const float fw = sw - (float)w0;
  int h1 = min(h0 + 1, 31); h0 = max(h0, 0);
  int w1 = min(w0 + 1, 31); w0 = max(w0, 0);

  const float c00 = (1.f - fh) * (1.f - fw), c01 = (1.f - fh) * fw;
  const float c10 = fh * (1.f - fw),         c11 = fh * fw;
  const int i00 = h0 * 32 + w0, i01 = h0 * 32 + w1;
  const int i10 = h1 * 32 + w0, i11 = h1 * 32 + w1;

  const float* xb = xt + (size_t)b * 64 * 1024;
  float xup[64];
#pragma unroll
  for (int c = 0; c < 64; ++c) {
    const float* xc = xb + (size_t)c * 1024;
    xup[c] = xc[i00] * c00 + xc[i01] * c01 + xc[i10] * c10 + xc[i11] * c11;
  }

  _Float16* Qp = Q + (size_t)p * E + eq * 16;
#pragma unroll
  for (int e0 = 0; e0 < 16; e0 += 8) {
    union { _Float16 h[8]; uint4 v; } pk;
#pragma unroll
    for (int j = 0; j < 8; ++j) {
      const int e = eq * 16 + e0 + j;
      float acc = qb[e];
#pragma unroll
      for (int c = 0; c < 64; ++c) acc += xup[c] * qw[e * 64 + c];
      pk.h[j] = (_Float16)(acc * SC);
    }
    *(uint4*)(Qp + e0) = pk.v;
  }
}

// ---------------------------------------------------------------------------
// Kernel 2: K and V projections. Thread handles (pixel, quarter):
// 16 K-channels + 8 V-channels. K [B][N][E]; V transposed [B][CO][N].
// ---------------------------------------------------------------------------
__global__ __launch_bounds__(256) void proj_kv_kernel(
    const float* __restrict__ xo,   // [B][32][N]
    const float* __restrict__ kw, const float* __restrict__ kb,
    const float* __restrict__ vw, const float* __restrict__ vb,
    _Float16* __restrict__ K, _Float16* __restrict__ Vt)
{
  const int tid = blockIdx.x * 256 + threadIdx.x;
  const int p   = tid >> 2;
  const int eq  = tid & 3;
  const int b   = p / N, n = p % N;

  const float* xb = xo + (size_t)b * CO * N + n;
  float x[32];
#pragma unroll
  for (int c = 0; c < 32; ++c) x[c] = xb[(size_t)c * N];

  _Float16* Kp = K + (size_t)p * E + eq * 16;
#pragma unroll
  for (int e0 = 0; e0 < 16; e0 += 8) {
    union { _Float16 h[8]; uint4 v; } pk;
#pragma unroll
    for (int j = 0; j < 8; ++j) {
      const int e = eq * 16 + e0 + j;
      float acc = kb[e];
#pragma unroll
      for (int c = 0; c < 32; ++c) acc += x[c] * kw[e * 32 + c];
      pk.h[j] = (_Float16)acc;
    }
    *(uint4*)(Kp + e0) = pk.v;
  }

  _Float16* Vp = Vt + (size_t)b * CO * N + n;
#pragma unroll
  for (int j = 0; j < 8; ++j) {
    const int o = eq * 8 + j;
    float acc = vb[o];
#pragma unroll
    for (int c = 0; c < 32; ++c) acc += x[c] * vw[o * 32 + c];
    Vp[(size_t)o * N] = (_Float16)acc;
  }
}

// ---------------------------------------------------------------------------
// Kernel 3: flash attention partials.
// Block = 4 waves = one 32-row group x 4-way m-split of one SPLIT=8 chunk.
// Wave body: swapped QK^T (S^T = mfma(K,Q)), shuffle-free PV via k-slot
// permutation (lane's PV B-frag = its own packed exps; V-frag 2x8B loads).
// Pairwise LDS combine; wave 0 writes f32x4 partials (SPLIT=8 volume).
// ---------------------------------------------------------------------------
__global__ __launch_bounds__(256, 8) void attn_kernel(
    const _Float16* __restrict__ Q,
    const _Float16* __restrict__ K,
    const _Float16* __restrict__ Vt,
    float* __restrict__ OutWS,   // [SPLIT][B][N][CO]
    float* __restrict__ SumWS)   // [SPLIT][B][N]
{
  __shared__ f32x4 lred[2][64][4];   // 8KB
  __shared__ float lsum[2][64][2];   // 1KB

  const int tid  = threadIdx.x;
  const int wave = tid >> 6, lane = tid & 63;
  const int r16  = lane & 15, g = lane >> 4;

  const int work  = blockIdx.x;
  const int chunk = work & (SPLIT - 1);
  const int rg    = work >> 3;            // 0..575 row-group
  const int b     = rg / 288;
  const int rowbase = (rg % 288) * 32;

  const _Float16* Qb = Q  + ((size_t)b * N + rowbase) * E;
  const _Float16* Kb = K  + (size_t)b * N * E;
  const _Float16* Vb = Vt + (size_t)b * CO * N;

  // Q B-fragments: 2 row-tiles x 2 k-steps (contiguous 16B per lane)
  f16x8 qf[2][2];
#pragma unroll
  for (int rt = 0; rt < 2; ++rt)
#pragma unroll
    for (int ks = 0; ks < 2; ++ks)
      qf[rt][ks] = *(const f16x8*)(Qb + (rt * 16 + r16) * E + ks * 32 + g * 8);

  f32x4 oacc[2][2];
#pragma unroll
  for (int a = 0; a < 2; ++a)
#pragma unroll
    for (int c = 0; c < 2; ++c) oacc[a][c] = (f32x4){0.f, 0.f, 0.f, 0.f};
  float sume[2] = {0.f, 0.f};

  const int mstart = chunk * MCHUNK + wave * MSUB;
#pragma unroll 2
  for (int m = mstart; m < mstart + MSUB; m += 32) {
    // K A-fragments: 2 m-tiles x 2 k-steps
    f16x8 kf[2][2];
#pragma unroll
    for (int mt = 0; mt < 2; ++mt)
#pragma unroll
      for (int ks = 0; ks < 2; ++ks)
        kf[mt][ks] = *(const f16x8*)(Kb + (size_t)(m + mt * 16 + r16) * E + ks * 32 + g * 8);

    // V A-fragments, permuted k-slots: elem j<4 -> m_local 4g+j,
    // j>=4 -> 16+4g+(j-4). Two 8B loads per o-tile.
    union { f16x4 h[2]; f16x8 v; } vf[2];
#pragma unroll
    for (int ot = 0; ot < 2; ++ot) {
      const _Float16* vp = Vb + (size_t)(ot * 16 + r16) * N + m + 4 * g;
      vf[ot].h[0] = *(const f16x4*)(vp);
      vf[ot].h[1] = *(const f16x4*)(vp + 16);
    }

#pragma unroll
    for (int rt = 0; rt < 2; ++rt) {
      f32x4 s0 = (f32x4){0.f, 0.f, 0.f, 0.f};
      f32x4 s1 = (f32x4){0.f, 0.f, 0.f, 0.f};
      s0 = MFMA(kf[0][0], qf[rt][0], s0);
      s0 = MFMA(kf[0][1], qf[rt][1], s0);
      s1 = MFMA(kf[1][0], qf[rt][0], s1);
      s1 = MFMA(kf[1][1], qf[rt][1], s1);

      float p0[4], p1[4];
#pragma unroll
      for (int i = 0; i < 4; ++i) {
        p0[i] = __builtin_amdgcn_exp2f(s0[i]);   // SC pre-folded into Q
        p1[i] = __builtin_amdgcn_exp2f(s1[i]);
      }
      sume[rt] += p0[0] + p0[1] + p0[2] + p0[3]
                + p1[0] + p1[1] + p1[2] + p1[3];

      // PV B-frag: lane's own values, permuted-k order (NO shuffles).
      union { unsigned u[4]; f16x8 v; } pb;
      pb.u[0] = __builtin_bit_cast(unsigned, __builtin_amdgcn_cvt_pkrtz(p0[0], p0[1]));
      pb.u[1] = __builtin_bit_cast(unsigned, __builtin_amdgcn_cvt_pkrtz(p0[2], p0[3]));
      pb.u[2] = __builtin_bit_cast(unsigned, __builtin_amdgcn_cvt_pkrtz(p1[0], p1[1]));
      pb.u[3] = __builtin_bit_cast(unsigned, __builtin_amdgcn_cvt_pkrtz(p1[2], p1[3]));

      oacc[rt][0] = MFMA(vf[0].v, pb.v, oacc[rt][0]);
      oacc[rt][1] = MFMA(vf[1].v, pb.v, oacc[rt][1]);
    }
  }

  // ---- combine the 4 m-split waves: (0+=2, 1+=3), then (0+=1) ----
  if (wave & 2) {
    const int s = wave - 2;
#pragma unroll
    for (int f = 0; f < 4; ++f) lred[s][lane][f] = oacc[f >> 1][f & 1];
    lsum[s][lane][0] = sume[0]; lsum[s][lane][1] = sume[1];
  }
  __syncthreads();
  if (!(wave & 2)) {
    const int s = wave;
#pragma unroll
    for (int f = 0; f < 4; ++f) oacc[f >> 1][f & 1] += lred[s][lane][f];
    sume[0] += lsum[s][lane][0]; sume[1] += lsum[s][lane][1];
  }
  __syncthreads();
  if (wave == 1) {
#pragma unroll
    for (int f = 0; f < 4; ++f) lred[0][lane][f] = oacc[f >> 1][f & 1];
    lsum[0][lane][0] = sume[0]; lsum[0][lane][1] = sume[1];
  }
  __syncthreads();
  if (wave == 0) {
#pragma unroll
    for (int f = 0; f < 4; ++f) oacc[f >> 1][f & 1] += lred[0][lane][f];
    sume[0] += lsum[0][lane][0]; sume[1] += lsum[0][lane][1];

    // reduce sumexp across the four 16-lane groups (each held different m)
#pragma unroll
    for (int rt = 0; rt < 2; ++rt) {
      sume[rt] += __shfl_xor(sume[rt], 16);
      sume[rt] += __shfl_xor(sume[rt], 32);
    }

    float* OW = OutWS + (size_t)(chunk * B + b) * N * CO;
    float* SW = SumWS + (size_t)(chunk * B + b) * N;
#pragma unroll
    for (int rt = 0; rt < 2; ++rt) {
      const int n = rowbase + rt * 16 + r16;
      if (g == 0) SW[n] = sume[rt];
#pragma unroll
      for (int ot = 0; ot < 2; ++ot)
        *(f32x4*)(OW + (size_t)n * CO + ot * 16 + 4 * g) = oacc[rt][ot];
    }
  }
}

// ---------------------------------------------------------------------------
// Kernel 4: combine split-m partials, normalize, out_w conv, BN, ReLU.
// Block: 64 pixels x 4 split-groups, dense float4 reads, LDS reduce.
// ---------------------------------------------------------------------------
__global__ __launch_bounds__(256) void epi_kernel(
    const float* __restrict__ OutWS, const float* __restrict__ SumWS,
    const float* __restrict__ ow, const float* __restrict__ gamma,
    const float* __restrict__ beta, const float* __restrict__ mean,
    const float* __restrict__ var, float* __restrict__ out)
{
  __shared__ float part[4][64][33];
  __shared__ float psum[4][64];

  const int tid  = threadIdx.x;
  const int nloc = tid & 63, grp = tid >> 6;
  const int pix  = blockIdx.x * 64 + nloc;
  const int b    = pix / N, n = pix % N;

  f32x4 acc[8];
#pragma unroll
  for (int j = 0; j < 8; ++j) acc[j] = (f32x4){0.f, 0.f, 0.f, 0.f};
  float ssum = 0.f;
#pragma unroll
  for (int k = 0; k < SPLIT / 4; ++k) {
    const int sc = grp * (SPLIT / 4) + k;
    const f32x4* src = (const f32x4*)(OutWS + ((size_t)(sc * B + b) * N + n) * CO);
#pragma unroll
    for (int j = 0; j < 8; ++j) acc[j] += src[j];
    ssum += SumWS[(size_t)(sc * B + b) * N + n];
  }
#pragma unroll
  for (int j = 0; j < 8; ++j)
#pragma unroll
    for (int i = 0; i < 4; ++i)
      part[grp][nloc][j * 4 + i] = acc[j][i];
  psum[grp][nloc] = ssum;
  __syncthreads();

  const float s = psum[0][nloc] + psum[1][nloc] + psum[2][nloc] + psum[3][nloc];
  const float inv = 1.f / s;
  float onr[CO];
#pragma unroll
  for (int o = 0; o < CO; ++o)
    onr[o] = (part[0][nloc][o] + part[1][nloc][o] +
              part[2][nloc][o] + part[3][nloc][o]) * inv;

#pragma unroll
  for (int i = 0; i < 16; ++i) {
    const int t = grp + 4 * i;
    float acc2 = 0.f;
#pragma unroll
    for (int o = 0; o < CO; ++o) acc2 += onr[o] * ow[t * CO + o];
    const float scl = gamma[t] * rsqrtf(var[t] + 1e-5f);
    const float bia = beta[t] - mean[t] * scl;
    const float gv  = acc2 * scl + bia;
    out[(size_t)(b * CT + t) * N + n] = fmaxf(gv, 0.f);
  }
}

// ---------------------------------------------------------------------------
extern "C" void kernel_launch(void* const* d_in, const int* in_sizes, int n_in,
                              void* d_out, int out_size, void* d_ws, size_t ws_size,
                              hipStream_t stream) {
  const float* xt = (const float*)d_in[0];
  const float* xo = (const float*)d_in[1];
  const float* qw = (const float*)d_in[2];
  const float* qb = (const float*)d_in[3];
  const float* kw = (const float*)d_in[4];
  const float* kb = (const float*)d_in[5];
  const float* vw = (const float*)d_in[6];
  const float* vb = (const float*)d_in[7];
  const float* ow = (const float*)d_in[8];
  const float* gm = (const float*)d_in[9];
  const float* bt = (const float*)d_in[10];
  const float* mn = (const float*)d_in[11];
  const float* vr = (const float*)d_in[12];

  char* ws = (char*)d_ws;
  _Float16* Qd  = (_Float16*)ws;  ws += (size_t)B * N * E * 2;            // 2.36 MB
  _Float16* Kd  = (_Float16*)ws;  ws += (size_t)B * N * E * 2;            // 2.36 MB
  _Float16* Vtd = (_Float16*)ws;  ws += (size_t)B * CO * N * 2;           // 1.18 MB
  float* OutWS  = (float*)ws;     ws += (size_t)SPLIT * B * N * CO * 4;   // 18.9 MB
  float* SumWS  = (float*)ws;                                             // 0.6 MB

  proj_q_kernel<<<(B * N * 4) / 256, 256, 0, stream>>>(xt, qw, qb, Qd);
  proj_kv_kernel<<<(B * N * 4) / 256, 256, 0, stream>>>(xo, kw, kb, vw, vb, Kd, Vtd);
  attn_kernel<<<(B * N / 32) * SPLIT, 256, 0, stream>>>(Qd, Kd, Vtd, OutWS, SumWS);
  epi_kernel<<<(B * N) / 64, 256, 0, stream>>>(OutWS, SumWS, ow, gm, bt, mn, vr,
                                               (float*)d_out);
}

// Round 7
// 269.474 us; speedup vs baseline: 1.6383x; 1.6383x over previous
//
#include <hip/hip_runtime.h>
#include <hip/hip_bf16.h>

// ---------------------------------------------------------------------------
// CrossAttentionBlock: bilinear 3x upsample -> QKV 1x1 projections ->
// full cross-attention (N=9216, E=64, Co=32) -> 1x1 conv + BN + ReLU.
// Flash-style, fp16 MFMA 16x16x32, fp32 accumulate, no-max softmax
// (scores bounded), split-m partials combined additively in epilogue.
//
// R7 vs R6: attn re-built on R1's shell (1152 blocks x 4 waves x 32 rows,
// SPLIT=8, scalar OutWS stores = proven 19MB exact) + LDS-staged K/V shared
// by the 4 waves (4x less global traffic; ds_read replaces 16-line-scatter
// loads), double-buffered T3-lite schedule, XOR-swizzle via pre-swizzled
// GLOBAL source + linear global_load_lds dest + swizzled reads (G21).
// Shuffle-free PV kept from R5. proj kernels reverted to R1 forms.
// ---------------------------------------------------------------------------

constexpr int B   = 2;
constexpr int N   = 9216;   // 96*96
constexpr int E   = 64;
constexpr int CO  = 32;
constexpr int CT  = 64;
constexpr int SPLIT  = 8;
constexpr int MCHUNK = N / SPLIT;        // 1152
constexpr int KVBLK  = 64;
constexpr int ROUNDS = MCHUNK / KVBLK;   // 18

typedef _Float16 f16x8 __attribute__((ext_vector_type(8)));
typedef _Float16 f16x4 __attribute__((ext_vector_type(4)));
typedef float    f32x4 __attribute__((ext_vector_type(4)));
typedef unsigned int u32;

#define MFMA(a, b, c) __builtin_amdgcn_mfma_f32_16x16x32_f16((a), (b), (c), 0, 0, 0)

// async global->LDS, 16B per lane, dest = base + lane*16 (wave-linear)
#define GLOAD16(gsrc, ldst)                                                     \
  __builtin_amdgcn_global_load_lds(                                             \
      (const __attribute__((address_space(1))) u32*)(gsrc),                     \
      (__attribute__((address_space(3))) u32*)(ldst), 16, 0, 0)

// exp(s/8) == exp2(s * SC); SC folded into Q projection weights.
#define SC 0.18033688011112042f

// ---------------------------------------------------------------------------
// Kernel 1: bilinear upsample (half-pixel, clamped) + Q projection.
// Q stored [B][N][E] fp16, PRE-SCALED by SC. One thread per output pixel.
// ---------------------------------------------------------------------------
__global__ __launch_bounds__(256) void proj_q_kernel(
    const float* __restrict__ xt,   // [B][64][32][32]
    const float* __restrict__ qw,   // [64][64]
    const float* __restrict__ qb,   // [64]
    _Float16* __restrict__ Q)
{
  const int p  = blockIdx.x * 256 + threadIdx.x;   // 0..18431
  const int b  = p / N, n = p % N;
  const int ho = n / 96, wo = n % 96;

  const float sh = (ho + 0.5f) * (1.0f / 3.0f) - 0.5f;
  const float sw = (wo + 0.5f) * (1.0f / 3.0f) - 0.5f;
  int h0 = (int)floorf(sh); const float fh = sh - (float)h0;
  int w0 = (int)floorf(sw); const float fw = sw - (float)w0;
  int h1 = min(h0 + 1, 31); h0 = max(h0, 0);
  int w1 = min(w0 + 1, 31); w0 = max(w0, 0);

  const float c00 = (1.f - fh) * (1.f - fw), c01 = (1.f - fh) * fw;
  const float c10 = fh * (1.f - fw),         c11 = fh * fw;
  const int i00 = h0 * 32 + w0, i01 = h0 * 32 + w1;
  const int i10 = h1 * 32 + w0, i11 = h1 * 32 + w1;

  const float* xb = xt + (size_t)b * 64 * 1024;
  float xup[64];
#pragma unroll
  for (int c = 0; c < 64; ++c) {
    const float* xc = xb + (size_t)c * 1024;
    xup[c] = xc[i00] * c00 + xc[i01] * c01 + xc[i10] * c10 + xc[i11] * c11;
  }

  _Float16* Qp = Q + (size_t)p * E;
  for (int e0 = 0; e0 < 64; e0 += 8) {
    union { _Float16 h[8]; uint4 v; } pk;
#pragma unroll
    for (int j = 0; j < 8; ++j) {
      const int e = e0 + j;
      float acc = qb[e];
#pragma unroll
      for (int c = 0; c < 64; ++c) acc += xup[c] * qw[e * 64 + c];
      pk.h[j] = (_Float16)(acc * SC);
    }
    *(uint4*)(Qp + e0) = pk.v;
  }
}

// ---------------------------------------------------------------------------
// Kernel 2: K and V projections from x_optical.
// K stored [B][N][E] fp16; V stored transposed [B][CO][N] fp16.
// ---------------------------------------------------------------------------
__global__ __launch_bounds__(256) void proj_kv_kernel(
    const float* __restrict__ xo,   // [B][32][N]
    const float* __restrict__ kw, const float* __restrict__ kb,
    const float* __restrict__ vw, const float* __restrict__ vb,
    _Float16* __restrict__ K, _Float16* __restrict__ Vt)
{
  const int p = blockIdx.x * 256 + threadIdx.x;
  const int b = p / N, n = p % N;

  const float* xb = xo + (size_t)b * CO * N + n;
  float x[32];
#pragma unroll
  for (int c = 0; c < 32; ++c) x[c] = xb[(size_t)c * N];

  _Float16* Kp = K + (size_t)p * E;
  for (int e0 = 0; e0 < 64; e0 += 8) {
    union { _Float16 h[8]; uint4 v; } pk;
#pragma unroll
    for (int j = 0; j < 8; ++j) {
      const int e = e0 + j;
      float acc = kb[e];
#pragma unroll
      for (int c = 0; c < 32; ++c) acc += x[c] * kw[e * 32 + c];
      pk.h[j] = (_Float16)acc;
    }
    *(uint4*)(Kp + e0) = pk.v;
  }

  _Float16* Vp = Vt + (size_t)b * CO * N + n;
#pragma unroll
  for (int o = 0; o < 32; ++o) {
    float acc = vb[o];
#pragma unroll
    for (int c = 0; c < 32; ++c) acc += x[c] * vw[o * 32 + c];
    Vp[(size_t)o * N] = (_Float16)acc;
  }
}

// ---------------------------------------------------------------------------
// Kernel 3: flash attention partials. 4 waves x 32 rows; all waves share the
// block's m-chunk. K/V double-buffered in LDS (XOR-swizzled: stored col-byte
// = actual ^ ((row&7)<<4)), staged via global_load_lds from pre-swizzled
// global addresses. Swapped QK^T; shuffle-free PV (k-slot permutation).
// ---------------------------------------------------------------------------
__global__ __launch_bounds__(256) void attn_kernel(
    const _Float16* __restrict__ Q,
    const _Float16* __restrict__ K,
    const _Float16* __restrict__ Vt,
    float* __restrict__ OutWS,   // [SPLIT][B][N][CO]
    float* __restrict__ SumWS)   // [SPLIT][B][N]
{
  __shared__ _Float16 Kl[2][KVBLK][64];   // 16 KB: [buf][m_local][e]
  __shared__ _Float16 Vl[2][CO][KVBLK];   //  8 KB: [buf][o][m_local]

  const int tid  = threadIdx.x;
  const int wave = tid >> 6, lane = tid & 63;
  const int r16  = lane & 15, g = lane >> 4;

  const int work  = blockIdx.x;
  const int chunk = work & (SPLIT - 1);
  const int t128  = work >> 3;            // 0..143
  const int b     = t128 / 72;
  const int rowbase = (t128 % 72) * 128 + wave * 32;

  const _Float16* Qb = Q  + ((size_t)b * N + rowbase) * E;
  const _Float16* Kb = K  + (size_t)b * N * E;
  const _Float16* Vb = Vt + (size_t)b * CO * N;

  // staging lane mapping: lane -> (row-in-8-group, 16B chunk), swizzled source
  const int sub = lane >> 3, c8 = lane & 7;
  const int swz = 8 * (c8 ^ sub);          // halfs offset of swizzled 16B chunk

  const int mstart = chunk * MCHUNK;

  // Q B-fragments: 2 row-tiles x 2 k-steps (contiguous 16B per lane)
  f16x8 qf[2][2];
#pragma unroll
  for (int rt = 0; rt < 2; ++rt)
#pragma unroll
    for (int ks = 0; ks < 2; ++ks)
      qf[rt][ks] = *(const f16x8*)(Qb + (rt * 16 + r16) * E + ks * 32 + g * 8);

  // prologue: stage round 0 into buf 0 (each wave: 2 K-instrs + 1 V-instr)
  {
    const _Float16* gk = Kb + (size_t)(mstart + 16 * wave + sub) * E + swz;
    GLOAD16(gk,         &Kl[0][16 * wave][0]);
    GLOAD16(gk + 8 * E, &Kl[0][16 * wave + 8][0]);
    const _Float16* gv = Vb + (size_t)(8 * wave + sub) * N + mstart + swz;
    GLOAD16(gv,         &Vl[0][8 * wave][0]);
  }

  f32x4 oacc[2][2];
#pragma unroll
  for (int a = 0; a < 2; ++a)
#pragma unroll
    for (int c = 0; c < 2; ++c) oacc[a][c] = (f32x4){0.f, 0.f, 0.f, 0.f};
  float sume[2] = {0.f, 0.f};

  // swizzled LDS read offsets (lane-constant)
  const int rsw   = (r16 & 7) << 4;                      // row XOR key (bytes)
  const int kcol0 = ((0 * 64 + g * 16) ^ rsw) >> 1;      // ks=0, halfs
  const int kcol1 = ((1 * 64 + g * 16) ^ rsw) >> 1;      // ks=1

  __syncthreads();

  int cur = 0;
  for (int r = 0; r < ROUNDS; ++r) {
    // issue next round's staging (overlaps with compute below)
    if (r + 1 < ROUNDS) {
      const int m0 = mstart + (r + 1) * KVBLK;
      const _Float16* gk = Kb + (size_t)(m0 + 16 * wave + sub) * E + swz;
      GLOAD16(gk,         &Kl[cur ^ 1][16 * wave][0]);
      GLOAD16(gk + 8 * E, &Kl[cur ^ 1][16 * wave + 8][0]);
      const _Float16* gv = Vb + (size_t)(8 * wave + sub) * N + m0 + swz;
      GLOAD16(gv,         &Vl[cur ^ 1][8 * wave][0]);
    }

    // compute current buffer: 2 sub-iterations of 32 m
#pragma unroll
    for (int it = 0; it < 2; ++it) {
      f16x8 kf[2][2];
#pragma unroll
      for (int mt = 0; mt < 2; ++mt) {
        const int krow = it * 32 + mt * 16 + r16;
        kf[mt][0] = *(const f16x8*)&Kl[cur][krow][kcol0];
        kf[mt][1] = *(const f16x8*)&Kl[cur][krow][kcol1];
      }
      union { f16x4 h[2]; f16x8 v; } vf[2];
#pragma unroll
      for (int ot = 0; ot < 2; ++ot) {
        const int vrow = ot * 16 + r16;
        const int v0 = ((it * 64 + 8 * g) ^ rsw) >> 1;
        const int v1 = ((it * 64 + 32 + 8 * g) ^ rsw) >> 1;
        vf[ot].h[0] = *(const f16x4*)&Vl[cur][vrow][v0];
        vf[ot].h[1] = *(const f16x4*)&Vl[cur][vrow][v1];
      }

#pragma unroll
      for (int rt = 0; rt < 2; ++rt) {
        f32x4 s0 = (f32x4){0.f, 0.f, 0.f, 0.f};
        f32x4 s1 = (f32x4){0.f, 0.f, 0.f, 0.f};
        s0 = MFMA(kf[0][0], qf[rt][0], s0);
        s0 = MFMA(kf[0][1], qf[rt][1], s0);
        s1 = MFMA(kf[1][0], qf[rt][0], s1);
        s1 = MFMA(kf[1][1], qf[rt][1], s1);

        float p0[4], p1[4];
#pragma unroll
        for (int i = 0; i < 4; ++i) {
          p0[i] = __builtin_amdgcn_exp2f(s0[i]);   // SC pre-folded into Q
          p1[i] = __builtin_amdgcn_exp2f(s1[i]);
        }
        sume[rt] += p0[0] + p0[1] + p0[2] + p0[3]
                  + p1[0] + p1[1] + p1[2] + p1[3];

        // PV B-frag: lane's own values, permuted-k order (NO shuffles).
        union { unsigned u[4]; f16x8 v; } pb;
        pb.u[0] = __builtin_bit_cast(unsigned, __builtin_amdgcn_cvt_pkrtz(p0[0], p0[1]));
        pb.u[1] = __builtin_bit_cast(unsigned, __builtin_amdgcn_cvt_pkrtz(p0[2], p0[3]));
        pb.u[2] = __builtin_bit_cast(unsigned, __builtin_amdgcn_cvt_pkrtz(p1[0], p1[1]));
        pb.u[3] = __builtin_bit_cast(unsigned, __builtin_amdgcn_cvt_pkrtz(p1[2], p1[3]));

        oacc[rt][0] = MFMA(vf[0].v, pb.v, oacc[rt][0]);
        oacc[rt][1] = MFMA(vf[1].v, pb.v, oacc[rt][1]);
      }
    }

    __syncthreads();   // drains vmcnt (staging done) + all waves past cur
    cur ^= 1;
  }

  // reduce sumexp across the four 16-lane groups (each held different m)
#pragma unroll
  for (int rt = 0; rt < 2; ++rt) {
    sume[rt] += __shfl_xor(sume[rt], 16);
    sume[rt] += __shfl_xor(sume[rt], 32);
  }

  float* OW = OutWS + (size_t)(chunk * B + b) * N * CO;
  float* SW = SumWS + (size_t)(chunk * B + b) * N;
#pragma unroll
  for (int rt = 0; rt < 2; ++rt) {
    const int n = rowbase + rt * 16 + r16;
    if (g == 0) SW[n] = sume[rt];
#pragma unroll
    for (int ot = 0; ot < 2; ++ot)
#pragma unroll
      for (int i = 0; i < 4; ++i)
        OW[(size_t)n * CO + ot * 16 + 4 * g + i] = oacc[rt][ot][i];
  }
}

// ---------------------------------------------------------------------------
// Kernel 4: combine split-m partials, normalize, out_w conv, BN, ReLU.
// Block: 64 pixels x 4 split-groups, dense float4 reads, LDS reduce.
// ---------------------------------------------------------------------------
__global__ __launch_bounds__(256) void epi_kernel(
    const float* __restrict__ OutWS, const float* __restrict__ SumWS,
    const float* __restrict__ ow, const float* __restrict__ gamma,
    const float* __restrict__ beta, const float* __restrict__ mean,
    const float* __restrict__ var, float* __restrict__ out)
{
  __shared__ float part[4][64][33];
  __shared__ float psum[4][64];

  const int tid  = threadIdx.x;
  const int nloc = tid & 63, grp = tid >> 6;
  const int pix  = blockIdx.x * 64 + nloc;
  const int b    = pix / N, n = pix % N;

  f32x4 acc[8];
#pragma unroll
  for (int j = 0; j < 8; ++j) acc[j] = (f32x4){0.f, 0.f, 0.f, 0.f};
  float ssum = 0.f;
#pragma unroll
  for (int k = 0; k < SPLIT / 4; ++k) {
    const int sc = grp * (SPLIT / 4) + k;
    const f32x4* src = (const f32x4*)(OutWS + ((size_t)(sc * B + b) * N + n) * CO);
#pragma unroll
    for (int j = 0; j < 8; ++j) acc[j] += src[j];
    ssum += SumWS[(size_t)(sc * B + b) * N + n];
  }
#pragma unroll
  for (int j = 0; j < 8; ++j)
#pragma unroll
    for (int i = 0; i < 4; ++i)
      part[grp][nloc][j * 4 + i] = acc[j][i];
  psum[grp][nloc] = ssum;
  __syncthreads();

  const float s = psum[0][nloc] + psum[1][nloc] + psum[2][nloc] + psum[3][nloc];
  const float inv = 1.f / s;
  float onr[CO];
#pragma unroll
  for (int o = 0; o < CO; ++o)
    onr[o] = (part[0][nloc][o] + part[1][nloc][o] +
              part[2][nloc][o] + part[3][nloc][o]) * inv;

#pragma unroll
  for (int i = 0; i < 16; ++i) {
    const int t = grp + 4 * i;
    float acc2 = 0.f;
#pragma unroll
    for (int o = 0; o < CO; ++o) acc2 += onr[o] * ow[t * CO + o];
    const float scl = gamma[t] * rsqrtf(var[t] + 1e-5f);
    const float bia = beta[t] - mean[t] * scl;
    const float gv  = acc2 * scl + bia;
    out[(size_t)(b * CT + t) * N + n] = fmaxf(gv, 0.f);
  }
}

// ---------------------------------------------------------------------------
extern "C" void kernel_launch(void* const* d_in, const int* in_sizes, int n_in,
                              void* d_out, int out_size, void* d_ws, size_t ws_size,
                              hipStream_t stream) {
  const float* xt = (const float*)d_in[0];
  const float* xo = (const float*)d_in[1];
  const float* qw = (const float*)d_in[2];
  const float* qb = (const float*)d_in[3];
  const float* kw = (const float*)d_in[4];
  const float* kb = (const float*)d_in[5];
  const float* vw = (const float*)d_in[6];
  const float* vb = (const float*)d_in[7];
  const float* ow = (const float*)d_in[8];
  const float* gm = (const float*)d_in[9];
  const float* bt = (const float*)d_in[10];
  const float* mn = (const float*)d_in[11];
  const float* vr = (const float*)d_in[12];

  char* ws = (char*)d_ws;
  _Float16* Qd  = (_Float16*)ws;  ws += (size_t)B * N * E * 2;            // 2.36 MB
  _Float16* Kd  = (_Float16*)ws;  ws += (size_t)B * N * E * 2;            // 2.36 MB
  _Float16* Vtd = (_Float16*)ws;  ws += (size_t)B * CO * N * 2;           // 1.18 MB
  float* OutWS  = (float*)ws;     ws += (size_t)SPLIT * B * N * CO * 4;   // 18.9 MB
  float* SumWS  = (float*)ws;                                             // 0.6 MB

  proj_q_kernel<<<(B * N) / 256, 256, 0, stream>>>(xt, qw, qb, Qd);
  proj_kv_kernel<<<(B * N) / 256, 256, 0, stream>>>(xo, kw, kb, vw, vb, Kd, Vtd);
  attn_kernel<<<(N / 128) * B * SPLIT, 256, 0, stream>>>(Qd, Kd, Vtd, OutWS, SumWS);
  epi_kernel<<<(B * N) / 64, 256, 0, stream>>>(OutWS, SumWS, ow, gm, bt, mn, vr,
                                               (float*)d_out);
}

// Round 8
// 212.847 us; speedup vs baseline: 2.0742x; 1.2660x over previous
//
#include <hip/hip_runtime.h>
#include <hip/hip_bf16.h>

// ---------------------------------------------------------------------------
// CrossAttentionBlock: bilinear 3x upsample -> QKV 1x1 projections ->
// full cross-attention (N=9216, E=64, Co=32) -> 1x1 conv + BN + ReLU.
// Flash-style, fp16 MFMA 16x16x32, fp32 accumulate, no-max softmax
// (scores bounded), split-m partials combined additively in epilogue.
//
// R8 vs R7 (269us; proj_q measured 77-84us, latency-bound gather):
//  - Q projection commuted: conv FIRST at 32x32 (proj_qsmall, trivial),
//    THEN bilinear upsample of the projected field (4 FMA/e vs 64; f32x4
//    corner loads, heavy L1 reuse). ~16x less work, vectorized loads.
//  - proj_kv quarter-split (4x waves) and fused with proj_qsmall into one
//    dispatch (block-range split).
//  - attn + epi byte-identical to R7.
// ---------------------------------------------------------------------------

constexpr int B   = 2;
constexpr int N   = 9216;   // 96*96
constexpr int E   = 64;
constexpr int CO  = 32;
constexpr int CT  = 64;
constexpr int SPLIT  = 8;
constexpr int MCHUNK = N / SPLIT;        // 1152
constexpr int KVBLK  = 64;
constexpr int ROUNDS = MCHUNK / KVBLK;   // 18

constexpr int KVB = (B * N * 4) / 256;   // 288 proj_kv blocks
constexpr int QSB = (B * 1024) / 256;    // 8 proj_qsmall blocks

typedef _Float16 f16x8 __attribute__((ext_vector_type(8)));
typedef _Float16 f16x4 __attribute__((ext_vector_type(4)));
typedef float    f32x4 __attribute__((ext_vector_type(4)));
typedef unsigned int u32;

#define MFMA(a, b, c) __builtin_amdgcn_mfma_f32_16x16x32_f16((a), (b), (c), 0, 0, 0)

// async global->LDS, 16B per lane, dest = base + lane*16 (wave-linear)
#define GLOAD16(gsrc, ldst)                                                     \
  __builtin_amdgcn_global_load_lds(                                             \
      (const __attribute__((address_space(1))) u32*)(gsrc),                     \
      (__attribute__((address_space(3))) u32*)(ldst), 16, 0, 0)

// exp(s/8) == exp2(s * SC); SC folded into the small Q projection.
#define SC 0.18033688011112042f

// ---------------------------------------------------------------------------
// Kernel 1 (fused): blocks [0,KVB): K/V projections (thread = pixel,quarter);
// blocks [KVB,KVB+QSB): small Q projection at 32x32 (thread = pixel).
// K stored [B][N][E] fp16; V transposed [B][CO][N] fp16; Qs [B*1024][64] f32.
// ---------------------------------------------------------------------------
__global__ __launch_bounds__(256) void proj_fused_kernel(
    const float* __restrict__ xo,   // [B][32][N]
    const float* __restrict__ kw, const float* __restrict__ kb,
    const float* __restrict__ vw, const float* __restrict__ vb,
    _Float16* __restrict__ K, _Float16* __restrict__ Vt,
    const float* __restrict__ xt,   // [B][64][32][32]
    const float* __restrict__ qw, const float* __restrict__ qb,
    float* __restrict__ Qs)         // [B*1024][64], SC-scaled
{
  if (blockIdx.x < KVB) {
    // ---- K/V projection, 4 quarter-threads per pixel ----
    const int tid = blockIdx.x * 256 + threadIdx.x;
    const int p   = tid >> 2;
    const int eq  = tid & 3;
    const int b   = p / N, n = p % N;

    const float* xb = xo + (size_t)b * CO * N + n;
    float x[32];
#pragma unroll
    for (int c = 0; c < 32; ++c) x[c] = xb[(size_t)c * N];

    _Float16* Kp = K + (size_t)p * E + eq * 16;
#pragma unroll
    for (int e0 = 0; e0 < 16; e0 += 8) {
      union { _Float16 h[8]; uint4 v; } pk;
#pragma unroll
      for (int j = 0; j < 8; ++j) {
        const int e = eq * 16 + e0 + j;
        float acc = kb[e];
#pragma unroll
        for (int c = 0; c < 32; ++c) acc += x[c] * kw[e * 32 + c];
        pk.h[j] = (_Float16)acc;
      }
      *(uint4*)(Kp + e0) = pk.v;
    }

    _Float16* Vp = Vt + (size_t)b * CO * N + n;
#pragma unroll
    for (int j = 0; j < 8; ++j) {
      const int o = eq * 8 + j;
      float acc = vb[o];
#pragma unroll
      for (int c = 0; c < 32; ++c) acc += x[c] * vw[o * 32 + c];
      Vp[(size_t)o * N] = (_Float16)acc;
    }
  } else {
    // ---- small Q projection at input resolution (32x32) ----
    const int pix = (blockIdx.x - KVB) * 256 + threadIdx.x;  // 0..2047
    const int b   = pix >> 10, p10 = pix & 1023;

    const float* xb = xt + (size_t)b * 64 * 1024 + p10;
    float x[64];
#pragma unroll
    for (int c = 0; c < 64; ++c) x[c] = xb[(size_t)c * 1024];

    float* Qp = Qs + (size_t)pix * 64;
    for (int e0 = 0; e0 < 64; e0 += 4) {
      f32x4 v;
#pragma unroll
      for (int j = 0; j < 4; ++j) {
        const int e = e0 + j;
        float acc = qb[e];
#pragma unroll
        for (int c = 0; c < 64; ++c) acc += x[c] * qw[e * 64 + c];
        v[j] = acc * SC;
      }
      *(f32x4*)(Qp + e0) = v;
    }
  }
}

// ---------------------------------------------------------------------------
// Kernel 2: bilinear 3x upsample of the PROJECTED field (conv commutes with
// bilinear interp). Thread = (output pixel, e-quarter): 4 corners x 16 e,
// f32x4 corner loads (L1-hot: 9 output px share corners), fp16 store.
// ---------------------------------------------------------------------------
__global__ __launch_bounds__(256) void upsample_q_kernel(
    const float* __restrict__ Qs,   // [B*1024][64], SC-scaled
    _Float16* __restrict__ Q)       // [B][N][E]
{
  const int tid = blockIdx.x * 256 + threadIdx.x;
  const int p   = tid >> 2;
  const int eq  = tid & 3;
  const int b   = p / N, n = p % N;
  const int ho  = n / 96, wo = n % 96;

  const float sh = (ho + 0.5f) * (1.0f / 3.0f) - 0.5f;
  const float sw = (wo + 0.5f) * (1.0f / 3.0f) - 0.5f;
  int h0 = (int)floorf(sh); const float fh = sh - (float)h0;
  int w0 = (int)floorf(sw); const float fw = sw - (float)w0;
  int h1 = min(h0 + 1, 31); h0 = max(h0, 0);
  int w1 = min(w0 + 1, 31); w0 = max(w0, 0);

  const float c00 = (1.f - fh) * (1.f - fw), c01 = (1.f - fh) * fw;
  const float c10 = fh * (1.f - fw),         c11 = fh * fw;

  const float* Qb = Qs + (size_t)b * 1024 * 64 + eq * 16;
  const f32x4* q00 = (const f32x4*)(Qb + (h0 * 32 + w0) * 64);
  const f32x4* q01 = (const f32x4*)(Qb + (h0 * 32 + w1) * 64);
  const f32x4* q10 = (const f32x4*)(Qb + (h1 * 32 + w0) * 64);
  const f32x4* q11 = (const f32x4*)(Qb + (h1 * 32 + w1) * 64);

  union { _Float16 h[16]; uint4 v[2]; } pk;
#pragma unroll
  for (int j4 = 0; j4 < 4; ++j4) {
    const f32x4 a = q00[j4] * c00 + q01[j4] * c01 + q10[j4] * c10 + q11[j4] * c11;
#pragma unroll
    for (int i = 0; i < 4; ++i) pk.h[4 * j4 + i] = (_Float16)a[i];
  }

  _Float16* Qp = Q + (size_t)p * E + eq * 16;
  *(uint4*)(Qp)     = pk.v[0];
  *(uint4*)(Qp + 8) = pk.v[1];
}

// ---------------------------------------------------------------------------
// Kernel 3: flash attention partials. (byte-identical to R7)
// 4 waves x 32 rows; K/V double-buffered in LDS (XOR-swizzled via
// pre-swizzled global source + linear global_load_lds dest + swizzled reads).
// Swapped QK^T; shuffle-free PV (k-slot permutation).
// ---------------------------------------------------------------------------
__global__ __launch_bounds__(256) void attn_kernel(
    const _Float16* __restrict__ Q,
    const _Float16* __restrict__ K,
    const _Float16* __restrict__ Vt,
    float* __restrict__ OutWS,   // [SPLIT][B][N][CO]
    float* __restrict__ SumWS)   // [SPLIT][B][N]
{
  __shared__ _Float16 Kl[2][KVBLK][64];   // 16 KB: [buf][m_local][e]
  __shared__ _Float16 Vl[2][CO][KVBLK];   //  8 KB: [buf][o][m_local]

  const int tid  = threadIdx.x;
  const int wave = tid >> 6, lane = tid & 63;
  const int r16  = lane & 15, g = lane >> 4;

  const int work  = blockIdx.x;
  const int chunk = work & (SPLIT - 1);
  const int t128  = work >> 3;            // 0..143
  const int b     = t128 / 72;
  const int rowbase = (t128 % 72) * 128 + wave * 32;

  const _Float16* Qb = Q  + ((size_t)b * N + rowbase) * E;
  const _Float16* Kb = K  + (size_t)b * N * E;
  const _Float16* Vb = Vt + (size_t)b * CO * N;

  // staging lane mapping: lane -> (row-in-8-group, 16B chunk), swizzled source
  const int sub = lane >> 3, c8 = lane & 7;
  const int swz = 8 * (c8 ^ sub);          // halfs offset of swizzled 16B chunk

  const int mstart = chunk * MCHUNK;

  // Q B-fragments: 2 row-tiles x 2 k-steps (contiguous 16B per lane)
  f16x8 qf[2][2];
#pragma unroll
  for (int rt = 0; rt < 2; ++rt)
#pragma unroll
    for (int ks = 0; ks < 2; ++ks)
      qf[rt][ks] = *(const f16x8*)(Qb + (rt * 16 + r16) * E + ks * 32 + g * 8);

  // prologue: stage round 0 into buf 0 (each wave: 2 K-instrs + 1 V-instr)
  {
    const _Float16* gk = Kb + (size_t)(mstart + 16 * wave + sub) * E + swz;
    GLOAD16(gk,         &Kl[0][16 * wave][0]);
    GLOAD16(gk + 8 * E, &Kl[0][16 * wave + 8][0]);
    const _Float16* gv = Vb + (size_t)(8 * wave + sub) * N + mstart + swz;
    GLOAD16(gv,         &Vl[0][8 * wave][0]);
  }

  f32x4 oacc[2][2];
#pragma unroll
  for (int a = 0; a < 2; ++a)
#pragma unroll
    for (int c = 0; c < 2; ++c) oacc[a][c] = (f32x4){0.f, 0.f, 0.f, 0.f};
  float sume[2] = {0.f, 0.f};

  // swizzled LDS read offsets (lane-constant)
  const int rsw   = (r16 & 7) << 4;                      // row XOR key (bytes)
  const int kcol0 = ((0 * 64 + g * 16) ^ rsw) >> 1;      // ks=0, halfs
  const int kcol1 = ((1 * 64 + g * 16) ^ rsw) >> 1;      // ks=1

  __syncthreads();

  int cur = 0;
  for (int r = 0; r < ROUNDS; ++r) {
    // issue next round's staging (overlaps with compute below)
    if (r + 1 < ROUNDS) {
      const int m0 = mstart + (r + 1) * KVBLK;
      const _Float16* gk = Kb + (size_t)(m0 + 16 * wave + sub) * E + swz;
      GLOAD16(gk,         &Kl[cur ^ 1][16 * wave][0]);
      GLOAD16(gk + 8 * E, &Kl[cur ^ 1][16 * wave + 8][0]);
      const _Float16* gv = Vb + (size_t)(8 * wave + sub) * N + m0 + swz;
      GLOAD16(gv,         &Vl[cur ^ 1][8 * wave][0]);
    }

    // compute current buffer: 2 sub-iterations of 32 m
#pragma unroll
    for (int it = 0; it < 2; ++it) {
      f16x8 kf[2][2];
#pragma unroll
      for (int mt = 0; mt < 2; ++mt) {
        const int krow = it * 32 + mt * 16 + r16;
        kf[mt][0] = *(const f16x8*)&Kl[cur][krow][kcol0];
        kf[mt][1] = *(const f16x8*)&Kl[cur][krow][kcol1];
      }
      union { f16x4 h[2]; f16x8 v; } vf[2];
#pragma unroll
      for (int ot = 0; ot < 2; ++ot) {
        const int vrow = ot * 16 + r16;
        const int v0 = ((it * 64 + 8 * g) ^ rsw) >> 1;
        const int v1 = ((it * 64 + 32 + 8 * g) ^ rsw) >> 1;
        vf[ot].h[0] = *(const f16x4*)&Vl[cur][vrow][v0];
        vf[ot].h[1] = *(const f16x4*)&Vl[cur][vrow][v1];
      }

#pragma unroll
      for (int rt = 0; rt < 2; ++rt) {
        f32x4 s0 = (f32x4){0.f, 0.f, 0.f, 0.f};
        f32x4 s1 = (f32x4){0.f, 0.f, 0.f, 0.f};
        s0 = MFMA(kf[0][0], qf[rt][0], s0);
        s0 = MFMA(kf[0][1], qf[rt][1], s0);
        s1 = MFMA(kf[1][0], qf[rt][0], s1);
        s1 = MFMA(kf[1][1], qf[rt][1], s1);

        float p0[4], p1[4];
#pragma unroll
        for (int i = 0; i < 4; ++i) {
          p0[i] = __builtin_amdgcn_exp2f(s0[i]);   // SC pre-folded into Q
          p1[i] = __builtin_amdgcn_exp2f(s1[i]);
        }
        sume[rt] += p0[0] + p0[1] + p0[2] + p0[3]
                  + p1[0] + p1[1] + p1[2] + p1[3];

        // PV B-frag: lane's own values, permuted-k order (NO shuffles).
        union { unsigned u[4]; f16x8 v; } pb;
        pb.u[0] = __builtin_bit_cast(unsigned, __builtin_amdgcn_cvt_pkrtz(p0[0], p0[1]));
        pb.u[1] = __builtin_bit_cast(unsigned, __builtin_amdgcn_cvt_pkrtz(p0[2], p0[3]));
        pb.u[2] = __builtin_bit_cast(unsigned, __builtin_amdgcn_cvt_pkrtz(p1[0], p1[1]));
        pb.u[3] = __builtin_bit_cast(unsigned, __builtin_amdgcn_cvt_pkrtz(p1[2], p1[3]));

        oacc[rt][0] = MFMA(vf[0].v, pb.v, oacc[rt][0]);
        oacc[rt][1] = MFMA(vf[1].v, pb.v, oacc[rt][1]);
      }
    }

    __syncthreads();   // drains vmcnt (staging done) + all waves past cur
    cur ^= 1;
  }

  // reduce sumexp across the four 16-lane groups (each held different m)
#pragma unroll
  for (int rt = 0; rt < 2; ++rt) {
    sume[rt] += __shfl_xor(sume[rt], 16);
    sume[rt] += __shfl_xor(sume[rt], 32);
  }

  float* OW = OutWS + (size_t)(chunk * B + b) * N * CO;
  float* SW = SumWS + (size_t)(chunk * B + b) * N;
#pragma unroll
  for (int rt = 0; rt < 2; ++rt) {
    const int n = rowbase + rt * 16 + r16;
    if (g == 0) SW[n] = sume[rt];
#pragma unroll
    for (int ot = 0; ot < 2; ++ot)
#pragma unroll
      for (int i = 0; i < 4; ++i)
        OW[(size_t)n * CO + ot * 16 + 4 * g + i] = oacc[rt][ot][i];
  }
}

// ---------------------------------------------------------------------------
// Kernel 4: combine split-m partials, normalize, out_w conv, BN, ReLU.
// (byte-identical to R7)
// ---------------------------------------------------------------------------
__global__ __launch_bounds__(256) void epi_kernel(
    const float* __restrict__ OutWS, const float* __restrict__ SumWS,
    const float* __restrict__ ow, const float* __restrict__ gamma,
    const float* __restrict__ beta, const float* __restrict__ mean,
    const float* __restrict__ var, float* __restrict__ out)
{
  __shared__ float part[4][64][33];
  __shared__ float psum[4][64];

  const int tid  = threadIdx.x;
  const int nloc = tid & 63, grp = tid >> 6;
  const int pix  = blockIdx.x * 64 + nloc;
  const int b    = pix / N, n = pix % N;

  f32x4 acc[8];
#pragma unroll
  for (int j = 0; j < 8; ++j) acc[j] = (f32x4){0.f, 0.f, 0.f, 0.f};
  float ssum = 0.f;
#pragma unroll
  for (int k = 0; k < SPLIT / 4; ++k) {
    const int sc = grp * (SPLIT / 4) + k;
    const f32x4* src = (const f32x4*)(OutWS + ((size_t)(sc * B + b) * N + n) * CO);
#pragma unroll
    for (int j = 0; j < 8; ++j) acc[j] += src[j];
    ssum += SumWS[(size_t)(sc * B + b) * N + n];
  }
#pragma unroll
  for (int j = 0; j < 8; ++j)
#pragma unroll
    for (int i = 0; i < 4; ++i)
      part[grp][nloc][j * 4 + i] = acc[j][i];
  psum[grp][nloc] = ssum;
  __syncthreads();

  const float s = psum[0][nloc] + psum[1][nloc] + psum[2][nloc] + psum[3][nloc];
  const float inv = 1.f / s;
  float onr[CO];
#pragma unroll
  for (int o = 0; o < CO; ++o)
    onr[o] = (part[0][nloc][o] + part[1][nloc][o] +
              part[2][nloc][o] + part[3][nloc][o]) * inv;

#pragma unroll
  for (int i = 0; i < 16; ++i) {
    const int t = grp + 4 * i;
    float acc2 = 0.f;
#pragma unroll
    for (int o = 0; o < CO; ++o) acc2 += onr[o] * ow[t * CO + o];
    const float scl = gamma[t] * rsqrtf(var[t] + 1e-5f);
    const float bia = beta[t] - mean[t] * scl;
    const float gv  = acc2 * scl + bia;
    out[(size_t)(b * CT + t) * N + n] = fmaxf(gv, 0.f);
  }
}

// ---------------------------------------------------------------------------
extern "C" void kernel_launch(void* const* d_in, const int* in_sizes, int n_in,
                              void* d_out, int out_size, void* d_ws, size_t ws_size,
                              hipStream_t stream) {
  const float* xt = (const float*)d_in[0];
  const float* xo = (const float*)d_in[1];
  const float* qw = (const float*)d_in[2];
  const float* qb = (const float*)d_in[3];
  const float* kw = (const float*)d_in[4];
  const float* kb = (const float*)d_in[5];
  const float* vw = (const float*)d_in[6];
  const float* vb = (const float*)d_in[7];
  const float* ow = (const float*)d_in[8];
  const float* gm = (const float*)d_in[9];
  const float* bt = (const float*)d_in[10];
  const float* mn = (const float*)d_in[11];
  const float* vr = (const float*)d_in[12];

  char* ws = (char*)d_ws;
  _Float16* Qd  = (_Float16*)ws;  ws += (size_t)B * N * E * 2;            // 2.36 MB
  _Float16* Kd  = (_Float16*)ws;  ws += (size_t)B * N * E * 2;            // 2.36 MB
  _Float16* Vtd = (_Float16*)ws;  ws += (size_t)B * CO * N * 2;           // 1.18 MB
  float* OutWS  = (float*)ws;     ws += (size_t)SPLIT * B * N * CO * 4;   // 18.9 MB
  float* SumWS  = (float*)ws;     ws += (size_t)SPLIT * B * N * 4;        // 0.6 MB
  float* Qs     = (float*)ws;                                             // 0.5 MB

  proj_fused_kernel<<<KVB + QSB, 256, 0, stream>>>(xo, kw, kb, vw, vb, Kd, Vtd,
                                                   xt, qw, qb, Qs);
  upsample_q_kernel<<<(B * N * 4) / 256, 256, 0, stream>>>(Qs, Qd);
  attn_kernel<<<(N / 128) * B * SPLIT, 256, 0, stream>>>(Qd, Kd, Vtd, OutWS, SumWS);
  epi_kernel<<<(B * N) / 64, 256, 0, stream>>>(OutWS, SumWS, ow, gm, bt, mn, vr,
                                               (float*)d_out);
}

// Round 9
// 202.097 us; speedup vs baseline: 2.1845x; 1.0532x over previous
//
#include <hip/hip_runtime.h>
#include <hip/hip_bf16.h>

// ---------------------------------------------------------------------------
// CrossAttentionBlock: bilinear 3x upsample -> QKV 1x1 projections ->
// full cross-attention (N=9216, E=64, Co=32) -> 1x1 conv + BN + ReLU.
// Flash-style, fp16 MFMA 16x16x32, fp32 accumulate, no-max softmax
// (scores bounded), split-m partials combined additively in epilogue.
//
// R9 vs R8 (213us; proj_fused measured 64us, occupancy 5%, VALU 3%):
//  - proj_fused rebuilt with WAVE-UNIFORM weight addressing (R8's eq=tid&3
//    made kw[e*32+c] lane-dependent -> 768 per-lane VMEM loads/thread; R1's
//    uniform-e form lets the compiler scalarize weights to s_load).
//    K / V / Qs split into disjoint block ranges (72+72+8): shorter chains,
//    2x blocks, x-loads lane-coalesced (lane = consecutive pixel).
//  - upsample_q, attn, epi byte-identical to R8.
// ---------------------------------------------------------------------------

constexpr int B   = 2;
constexpr int N   = 9216;   // 96*96
constexpr int E   = 64;
constexpr int CO  = 32;
constexpr int CT  = 64;
constexpr int SPLIT  = 8;
constexpr int MCHUNK = N / SPLIT;        // 1152
constexpr int KVBLK  = 64;
constexpr int ROUNDS = MCHUNK / KVBLK;   // 18

constexpr int KB_BLK = (B * N) / 256;    // 72  K-projection blocks
constexpr int VB_BLK = (B * N) / 256;    // 72  V-projection blocks
constexpr int QS_BLK = (B * 1024) / 256; // 8   Qs-projection blocks

typedef _Float16 f16x8 __attribute__((ext_vector_type(8)));
typedef _Float16 f16x4 __attribute__((ext_vector_type(4)));
typedef float    f32x4 __attribute__((ext_vector_type(4)));
typedef unsigned int u32;

#define MFMA(a, b, c) __builtin_amdgcn_mfma_f32_16x16x32_f16((a), (b), (c), 0, 0, 0)

// async global->LDS, 16B per lane, dest = base + lane*16 (wave-linear)
#define GLOAD16(gsrc, ldst)                                                     \
  __builtin_amdgcn_global_load_lds(                                             \
      (const __attribute__((address_space(1))) u32*)(gsrc),                     \
      (__attribute__((address_space(3))) u32*)(ldst), 16, 0, 0)

// exp(s/8) == exp2(s * SC); SC folded into the small Q projection.
#define SC 0.18033688011112042f

// ---------------------------------------------------------------------------
// Kernel 1 (fused, block-range split; ALL weight reads wave-uniform):
//  [0,KB_BLK):          K projection, thread = pixel, e = 0..63
//  [KB_BLK,+VB_BLK):    V projection, thread = pixel, o = 0..31
//  [KB_BLK+VB_BLK,+8):  small Q projection at 32x32, thread = pixel
// ---------------------------------------------------------------------------
__global__ __launch_bounds__(256) void proj_fused_kernel(
    const float* __restrict__ xo,   // [B][32][N]
    const float* __restrict__ kw, const float* __restrict__ kb,
    const float* __restrict__ vw, const float* __restrict__ vb,
    _Float16* __restrict__ K, _Float16* __restrict__ Vt,
    const float* __restrict__ xt,   // [B][64][32][32]
    const float* __restrict__ qw, const float* __restrict__ qb,
    float* __restrict__ Qs)         // [B*1024][64], SC-scaled
{
  if (blockIdx.x < KB_BLK) {
    // ---- K projection: thread = pixel, uniform e ----
    const int p = blockIdx.x * 256 + threadIdx.x;
    const int b = p / N, n = p % N;

    const float* xb = xo + (size_t)b * CO * N + n;
    float x[32];
#pragma unroll
    for (int c = 0; c < 32; ++c) x[c] = xb[(size_t)c * N];

    _Float16* Kp = K + (size_t)p * E;
#pragma unroll
    for (int e0 = 0; e0 < 64; e0 += 8) {
      union { _Float16 h[8]; uint4 v; } pk;
#pragma unroll
      for (int j = 0; j < 8; ++j) {
        const int e = e0 + j;
        float acc = kb[e];
#pragma unroll
        for (int c = 0; c < 32; ++c) acc += x[c] * kw[e * 32 + c];
        pk.h[j] = (_Float16)acc;
      }
      *(uint4*)(Kp + e0) = pk.v;
    }
  } else if (blockIdx.x < KB_BLK + VB_BLK) {
    // ---- V projection: thread = pixel, uniform o ----
    const int p = (blockIdx.x - KB_BLK) * 256 + threadIdx.x;
    const int b = p / N, n = p % N;

    const float* xb = xo + (size_t)b * CO * N + n;
    float x[32];
#pragma unroll
    for (int c = 0; c < 32; ++c) x[c] = xb[(size_t)c * N];

    _Float16* Vp = Vt + (size_t)b * CO * N + n;
#pragma unroll
    for (int o = 0; o < 32; ++o) {
      float acc = vb[o];
#pragma unroll
      for (int c = 0; c < 32; ++c) acc += x[c] * vw[o * 32 + c];
      Vp[(size_t)o * N] = (_Float16)acc;
    }
  } else {
    // ---- small Q projection at input resolution (32x32), uniform e ----
    const int pix = (blockIdx.x - KB_BLK - VB_BLK) * 256 + threadIdx.x;
    const int b   = pix >> 10, p10 = pix & 1023;

    const float* xb = xt + (size_t)b * 64 * 1024 + p10;
    float x[64];
#pragma unroll
    for (int c = 0; c < 64; ++c) x[c] = xb[(size_t)c * 1024];

    float* Qp = Qs + (size_t)pix * 64;
#pragma unroll
    for (int e0 = 0; e0 < 64; e0 += 4) {
      f32x4 v;
#pragma unroll
      for (int j = 0; j < 4; ++j) {
        const int e = e0 + j;
        float acc = qb[e];
#pragma unroll
        for (int c = 0; c < 64; ++c) acc += x[c] * qw[e * 64 + c];
        v[j] = acc * SC;
      }
      *(f32x4*)(Qp + e0) = v;
    }
  }
}

// ---------------------------------------------------------------------------
// Kernel 2: bilinear 3x upsample of the PROJECTED field (conv commutes with
// bilinear interp). Thread = (output pixel, e-quarter): 4 corners x 16 e,
// f32x4 corner loads (L1-hot: 9 output px share corners), fp16 store.
// ---------------------------------------------------------------------------
__global__ __launch_bounds__(256) void upsample_q_kernel(
    const float* __restrict__ Qs,   // [B*1024][64], SC-scaled
    _Float16* __restrict__ Q)       // [B][N][E]
{
  const int tid = blockIdx.x * 256 + threadIdx.x;
  const int p   = tid >> 2;
  const int eq  = tid & 3;
  const int b   = p / N, n = p % N;
  const int ho  = n / 96, wo = n % 96;

  const float sh = (ho + 0.5f) * (1.0f / 3.0f) - 0.5f;
  const float sw = (wo + 0.5f) * (1.0f / 3.0f) - 0.5f;
  int h0 = (int)floorf(sh); const float fh = sh - (float)h0;
  int w0 = (int)floorf(sw); const float fw = sw - (float)w0;
  int h1 = min(h0 + 1, 31); h0 = max(h0, 0);
  int w1 = min(w0 + 1, 31); w0 = max(w0, 0);

  const float c00 = (1.f - fh) * (1.f - fw), c01 = (1.f - fh) * fw;
  const float c10 = fh * (1.f - fw),         c11 = fh * fw;

  const float* Qb = Qs + (size_t)b * 1024 * 64 + eq * 16;
  const f32x4* q00 = (const f32x4*)(Qb + (h0 * 32 + w0) * 64);
  const f32x4* q01 = (const f32x4*)(Qb + (h0 * 32 + w1) * 64);
  const f32x4* q10 = (const f32x4*)(Qb + (h1 * 32 + w0) * 64);
  const f32x4* q11 = (const f32x4*)(Qb + (h1 * 32 + w1) * 64);

  union { _Float16 h[16]; uint4 v[2]; } pk;
#pragma unroll
  for (int j4 = 0; j4 < 4; ++j4) {
    const f32x4 a = q00[j4] * c00 + q01[j4] * c01 + q10[j4] * c10 + q11[j4] * c11;
#pragma unroll
    for (int i = 0; i < 4; ++i) pk.h[4 * j4 + i] = (_Float16)a[i];
  }

  _Float16* Qp = Q + (size_t)p * E + eq * 16;
  *(uint4*)(Qp)     = pk.v[0];
  *(uint4*)(Qp + 8) = pk.v[1];
}

// ---------------------------------------------------------------------------
// Kernel 3: flash attention partials. (byte-identical to R7/R8)
// 4 waves x 32 rows; K/V double-buffered in LDS (XOR-swizzled via
// pre-swizzled global source + linear global_load_lds dest + swizzled reads).
// Swapped QK^T; shuffle-free PV (k-slot permutation).
// ---------------------------------------------------------------------------
__global__ __launch_bounds__(256) void attn_kernel(
    const _Float16* __restrict__ Q,
    const _Float16* __restrict__ K,
    const _Float16* __restrict__ Vt,
    float* __restrict__ OutWS,   // [SPLIT][B][N][CO]
    float* __restrict__ SumWS)   // [SPLIT][B][N]
{
  __shared__ _Float16 Kl[2][KVBLK][64];   // 16 KB: [buf][m_local][e]
  __shared__ _Float16 Vl[2][CO][KVBLK];   //  8 KB: [buf][o][m_local]

  const int tid  = threadIdx.x;
  const int wave = tid >> 6, lane = tid & 63;
  const int r16  = lane & 15, g = lane >> 4;

  const int work  = blockIdx.x;
  const int chunk = work & (SPLIT - 1);
  const int t128  = work >> 3;            // 0..143
  const int b     = t128 / 72;
  const int rowbase = (t128 % 72) * 128 + wave * 32;

  const _Float16* Qb = Q  + ((size_t)b * N + rowbase) * E;
  const _Float16* Kb = K  + (size_t)b * N * E;
  const _Float16* Vb = Vt + (size_t)b * CO * N;

  // staging lane mapping: lane -> (row-in-8-group, 16B chunk), swizzled source
  const int sub = lane >> 3, c8 = lane & 7;
  const int swz = 8 * (c8 ^ sub);          // halfs offset of swizzled 16B chunk

  const int mstart = chunk * MCHUNK;

  // Q B-fragments: 2 row-tiles x 2 k-steps (contiguous 16B per lane)
  f16x8 qf[2][2];
#pragma unroll
  for (int rt = 0; rt < 2; ++rt)
#pragma unroll
    for (int ks = 0; ks < 2; ++ks)
      qf[rt][ks] = *(const f16x8*)(Qb + (rt * 16 + r16) * E + ks * 32 + g * 8);

  // prologue: stage round 0 into buf 0 (each wave: 2 K-instrs + 1 V-instr)
  {
    const _Float16* gk = Kb + (size_t)(mstart + 16 * wave + sub) * E + swz;
    GLOAD16(gk,         &Kl[0][16 * wave][0]);
    GLOAD16(gk + 8 * E, &Kl[0][16 * wave + 8][0]);
    const _Float16* gv = Vb + (size_t)(8 * wave + sub) * N + mstart + swz;
    GLOAD16(gv,         &Vl[0][8 * wave][0]);
  }

  f32x4 oacc[2][2];
#pragma unroll
  for (int a = 0; a < 2; ++a)
#pragma unroll
    for (int c = 0; c < 2; ++c) oacc[a][c] = (f32x4){0.f, 0.f, 0.f, 0.f};
  float sume[2] = {0.f, 0.f};

  // swizzled LDS read offsets (lane-constant)
  const int rsw   = (r16 & 7) << 4;                      // row XOR key (bytes)
  const int kcol0 = ((0 * 64 + g * 16) ^ rsw) >> 1;      // ks=0, halfs
  const int kcol1 = ((1 * 64 + g * 16) ^ rsw) >> 1;      // ks=1

  __syncthreads();

  int cur = 0;
  for (int r = 0; r < ROUNDS; ++r) {
    // issue next round's staging (overlaps with compute below)
    if (r + 1 < ROUNDS) {
      const int m0 = mstart + (r + 1) * KVBLK;
      const _Float16* gk = Kb + (size_t)(m0 + 16 * wave + sub) * E + swz;
      GLOAD16(gk,         &Kl[cur ^ 1][16 * wave][0]);
      GLOAD16(gk + 8 * E, &Kl[cur ^ 1][16 * wave + 8][0]);
      const _Float16* gv = Vb + (size_t)(8 * wave + sub) * N + m0 + swz;
      GLOAD16(gv,         &Vl[cur ^ 1][8 * wave][0]);
    }

    // compute current buffer: 2 sub-iterations of 32 m
#pragma unroll
    for (int it = 0; it < 2; ++it) {
      f16x8 kf[2][2];
#pragma unroll
      for (int mt = 0; mt < 2; ++mt) {
        const int krow = it * 32 + mt * 16 + r16;
        kf[mt][0] = *(const f16x8*)&Kl[cur][krow][kcol0];
        kf[mt][1] = *(const f16x8*)&Kl[cur][krow][kcol1];
      }
      union { f16x4 h[2]; f16x8 v; } vf[2];
#pragma unroll
      for (int ot = 0; ot < 2; ++ot) {
        const int vrow = ot * 16 + r16;
        const int v0 = ((it * 64 + 8 * g) ^ rsw) >> 1;
        const int v1 = ((it * 64 + 32 + 8 * g) ^ rsw) >> 1;
        vf[ot].h[0] = *(const f16x4*)&Vl[cur][vrow][v0];
        vf[ot].h[1] = *(const f16x4*)&Vl[cur][vrow][v1];
      }

#pragma unroll
      for (int rt = 0; rt < 2; ++rt) {
        f32x4 s0 = (f32x4){0.f, 0.f, 0.f, 0.f};
        f32x4 s1 = (f32x4){0.f, 0.f, 0.f, 0.f};
        s0 = MFMA(kf[0][0], qf[rt][0], s0);
        s0 = MFMA(kf[0][1], qf[rt][1], s0);
        s1 = MFMA(kf[1][0], qf[rt][0], s1);
        s1 = MFMA(kf[1][1], qf[rt][1], s1);

        float p0[4], p1[4];
#pragma unroll
        for (int i = 0; i < 4; ++i) {
          p0[i] = __builtin_amdgcn_exp2f(s0[i]);   // SC pre-folded into Q
          p1[i] = __builtin_amdgcn_exp2f(s1[i]);
        }
        sume[rt] += p0[0] + p0[1] + p0[2] + p0[3]
                  + p1[0] + p1[1] + p1[2] + p1[3];

        // PV B-frag: lane's own values, permuted-k order (NO shuffles).
        union { unsigned u[4]; f16x8 v; } pb;
        pb.u[0] = __builtin_bit_cast(unsigned, __builtin_amdgcn_cvt_pkrtz(p0[0], p0[1]));
        pb.u[1] = __builtin_bit_cast(unsigned, __builtin_amdgcn_cvt_pkrtz(p0[2], p0[3]));
        pb.u[2] = __builtin_bit_cast(unsigned, __builtin_amdgcn_cvt_pkrtz(p1[0], p1[1]));
        pb.u[3] = __builtin_bit_cast(unsigned, __builtin_amdgcn_cvt_pkrtz(p1[2], p1[3]));

        oacc[rt][0] = MFMA(vf[0].v, pb.v, oacc[rt][0]);
        oacc[rt][1] = MFMA(vf[1].v, pb.v, oacc[rt][1]);
      }
    }

    __syncthreads();   // drains vmcnt (staging done) + all waves past cur
    cur ^= 1;
  }

  // reduce sumexp across the four 16-lane groups (each held different m)
#pragma unroll
  for (int rt = 0; rt < 2; ++rt) {
    sume[rt] += __shfl_xor(sume[rt], 16);
    sume[rt] += __shfl_xor(sume[rt], 32);
  }

  float* OW = OutWS + (size_t)(chunk * B + b) * N * CO;
  float* SW = SumWS + (size_t)(chunk * B + b) * N;
#pragma unroll
  for (int rt = 0; rt < 2; ++rt) {
    const int n = rowbase + rt * 16 + r16;
    if (g == 0) SW[n] = sume[rt];
#pragma unroll
    for (int ot = 0; ot < 2; ++ot)
#pragma unroll
      for (int i = 0; i < 4; ++i)
        OW[(size_t)n * CO + ot * 16 + 4 * g + i] = oacc[rt][ot][i];
  }
}

// ---------------------------------------------------------------------------
// Kernel 4: combine split-m partials, normalize, out_w conv, BN, ReLU.
// (byte-identical to R7/R8)
// ---------------------------------------------------------------------------
__global__ __launch_bounds__(256) void epi_kernel(
    const float* __restrict__ OutWS, const float* __restrict__ SumWS,
    const float* __restrict__ ow, const float* __restrict__ gamma,
    const float* __restrict__ beta, const float* __restrict__ mean,
    const float* __restrict__ var, float* __restrict__ out)
{
  __shared__ float part[4][64][33];
  __shared__ float psum[4][64];

  const int tid  = threadIdx.x;
  const int nloc = tid & 63, grp = tid >> 6;
  const int pix  = blockIdx.x * 64 + nloc;
  const int b    = pix / N, n = pix % N;

  f32x4 acc[8];
#pragma unroll
  for (int j = 0; j < 8; ++j) acc[j] = (f32x4){0.f, 0.f, 0.f, 0.f};
  float ssum = 0.f;
#pragma unroll
  for (int k = 0; k < SPLIT / 4; ++k) {
    const int sc = grp * (SPLIT / 4) + k;
    const f32x4* src = (const f32x4*)(OutWS + ((size_t)(sc * B + b) * N + n) * CO);
#pragma unroll
    for (int j = 0; j < 8; ++j) acc[j] += src[j];
    ssum += SumWS[(size_t)(sc * B + b) * N + n];
  }
#pragma unroll
  for (int j = 0; j < 8; ++j)
#pragma unroll
    for (int i = 0; i < 4; ++i)
      part[grp][nloc][j * 4 + i] = acc[j][i];
  psum[grp][nloc] = ssum;
  __syncthreads();

  const float s = psum[0][nloc] + psum[1][nloc] + psum[2][nloc] + psum[3][nloc];
  const float inv = 1.f / s;
  float onr[CO];
#pragma unroll
  for (int o = 0; o < CO; ++o)
    onr[o] = (part[0][nloc][o] + part[1][nloc][o] +
              part[2][nloc][o] + part[3][nloc][o]) * inv;

#pragma unroll
  for (int i = 0; i < 16; ++i) {
    const int t = grp + 4 * i;
    float acc2 = 0.f;
#pragma unroll
    for (int o = 0; o < CO; ++o) acc2 += onr[o] * ow[t * CO + o];
    const float scl = gamma[t] * rsqrtf(var[t] + 1e-5f);
    const float bia = beta[t] - mean[t] * scl;
    const float gv  = acc2 * scl + bia;
    out[(size_t)(b * CT + t) * N + n] = fmaxf(gv, 0.f);
  }
}

// ---------------------------------------------------------------------------
extern "C" void kernel_launch(void* const* d_in, const int* in_sizes, int n_in,
                              void* d_out, int out_size, void* d_ws, size_t ws_size,
                              hipStream_t stream) {
  const float* xt = (const float*)d_in[0];
  const float* xo = (const float*)d_in[1];
  const float* qw = (const float*)d_in[2];
  const float* qb = (const float*)d_in[3];
  const float* kw = (const float*)d_in[4];
  const float* kb = (const float*)d_in[5];
  const float* vw = (const float*)d_in[6];
  const float* vb = (const float*)d_in[7];
  const float* ow = (const float*)d_in[8];
  const float* gm = (const float*)d_in[9];
  const float* bt = (const float*)d_in[10];
  const float* mn = (const float*)d_in[11];
  const float* vr = (const float*)d_in[12];

  char* ws = (char*)d_ws;
  _Float16* Qd  = (_Float16*)ws;  ws += (size_t)B * N * E * 2;            // 2.36 MB
  _Float16* Kd  = (_Float16*)ws;  ws += (size_t)B * N * E * 2;            // 2.36 MB
  _Float16* Vtd = (_Float16*)ws;  ws += (size_t)B * CO * N * 2;           // 1.18 MB
  float* OutWS  = (float*)ws;     ws += (size_t)SPLIT * B * N * CO * 4;   // 18.9 MB
  float* SumWS  = (float*)ws;     ws += (size_t)SPLIT * B * N * 4;        // 0.6 MB
  float* Qs     = (float*)ws;                                             // 0.5 MB

  proj_fused_kernel<<<KB_BLK + VB_BLK + QS_BLK, 256, 0, stream>>>(
      xo, kw, kb, vw, vb, Kd, Vtd, xt, qw, qb, Qs);
  upsample_q_kernel<<<(B * N * 4) / 256, 256, 0, stream>>>(Qs, Qd);
  attn_kernel<<<(N / 128) * B * SPLIT, 256, 0, stream>>>(Qd, Kd, Vtd, OutWS, SumWS);
  epi_kernel<<<(B * N) / 64, 256, 0, stream>>>(OutWS, SumWS, ow, gm, bt, mn, vr,
                                               (float*)d_out);
}

// Round 10
// 171.661 us; speedup vs baseline: 2.5718x; 1.1773x over previous
//
#include <hip/hip_runtime.h>
#include <hip/hip_bf16.h>

// ---------------------------------------------------------------------------
// CrossAttentionBlock: bilinear 3x upsample -> QKV 1x1 projections ->
// full cross-attention (N=9216, E=64, Co=32) -> 1x1 conv + BN + ReLU.
// Flash-style, fp16 MFMA 16x16x32, fp32 accumulate, no-max softmax
// (scores bounded), split-m partials combined additively in epilogue.
//
// R10 vs R9 (202us; proj_fused 60us latency-bound @0.6 waves/SIMD + serial
// s_load batches; attn 59.5us stall-bound @4.5 waves/SIMD supply):
//  - proj_fused: e/o-ranges split across blocks (block-uniform -> weights
//    stay scalar), outer loops #pragma unroll 1 (bounded code, shorter
//    serial chains). 288 K-blocks(16e) + 288 V-blocks(8o) + 32 Qs-blocks.
//  - attn/epi: templated SPLIT, prefer 16 (9216 waves = 9/SIMD supply,
//    ROUNDS=9) with runtime ws_size fallback to 8. Store pattern unchanged
//    (proven amplification-free: full 128B rows).
//  - upsample_q byte-identical to R9.
// ---------------------------------------------------------------------------

constexpr int B   = 2;
constexpr int N   = 9216;   // 96*96
constexpr int E   = 64;
constexpr int CO  = 32;
constexpr int CT  = 64;
constexpr int KVBLK = 64;

constexpr int KP_BLK = 288;  // K proj: 72 px-blocks x 4 e-groups
constexpr int VP_BLK = 288;  // V proj: 72 px-blocks x 4 o-groups
constexpr int QP_BLK = 32;   // Qs proj: 8 px-blocks x 4 e-groups

typedef _Float16 f16x8 __attribute__((ext_vector_type(8)));
typedef _Float16 f16x4 __attribute__((ext_vector_type(4)));
typedef float    f32x4 __attribute__((ext_vector_type(4)));
typedef unsigned int u32;

#define MFMA(a, b, c) __builtin_amdgcn_mfma_f32_16x16x32_f16((a), (b), (c), 0, 0, 0)

// async global->LDS, 16B per lane, dest = base + lane*16 (wave-linear)
#define GLOAD16(gsrc, ldst)                                                     \
  __builtin_amdgcn_global_load_lds(                                             \
      (const __attribute__((address_space(1))) u32*)(gsrc),                     \
      (__attribute__((address_space(3))) u32*)(ldst), 16, 0, 0)

// exp(s/8) == exp2(s * SC); SC folded into the small Q projection.
#define SC 0.18033688011112042f

// ---------------------------------------------------------------------------
// Kernel 1 (fused projections, block-range split, block-uniform channels):
//  [0,288):   K proj  — block = (72 px-blk) x (4 e-groups of 16)
//  [288,576): V proj  — block = (72 px-blk) x (4 o-groups of 8)
//  [576,608): Qs proj — block = (8 px-blk)  x (4 e-groups of 16)
// ---------------------------------------------------------------------------
__global__ __launch_bounds__(256) void proj_fused_kernel(
    const float* __restrict__ xo,   // [B][32][N]
    const float* __restrict__ kw, const float* __restrict__ kb,
    const float* __restrict__ vw, const float* __restrict__ vb,
    _Float16* __restrict__ K, _Float16* __restrict__ Vt,
    const float* __restrict__ xt,   // [B][64][32][32]
    const float* __restrict__ qw, const float* __restrict__ qb,
    float* __restrict__ Qs)         // [B*1024][64], SC-scaled
{
  const int bid = blockIdx.x;
  if (bid < KP_BLK) {
    // ---- K projection: 16 e per block (block-uniform e-range) ----
    const int p      = (bid >> 2) * 256 + threadIdx.x;
    const int estart = (bid & 3) * 16;
    const int b = p / N, n = p % N;

    const float* xb = xo + (size_t)b * CO * N + n;
    float x[32];
#pragma unroll
    for (int c = 0; c < 32; ++c) x[c] = xb[(size_t)c * N];

    _Float16* Kp = K + (size_t)p * E + estart;
#pragma unroll 1
    for (int e0 = 0; e0 < 16; e0 += 8) {
      union { _Float16 h[8]; uint4 v; } pk;
#pragma unroll
      for (int j = 0; j < 8; ++j) {
        const int e = estart + e0 + j;
        float acc = kb[e];
#pragma unroll
        for (int c = 0; c < 32; ++c) acc += x[c] * kw[e * 32 + c];
        pk.h[j] = (_Float16)acc;
      }
      *(uint4*)(Kp + e0) = pk.v;
    }
  } else if (bid < KP_BLK + VP_BLK) {
    // ---- V projection: 8 o per block (block-uniform o-range) ----
    const int vbid   = bid - KP_BLK;
    const int p      = (vbid >> 2) * 256 + threadIdx.x;
    const int ostart = (vbid & 3) * 8;
    const int b = p / N, n = p % N;

    const float* xb = xo + (size_t)b * CO * N + n;
    float x[32];
#pragma unroll
    for (int c = 0; c < 32; ++c) x[c] = xb[(size_t)c * N];

    _Float16* Vp = Vt + (size_t)b * CO * N + n;
#pragma unroll 1
    for (int j = 0; j < 8; ++j) {
      const int o = ostart + j;
      float acc = vb[o];
#pragma unroll
      for (int c = 0; c < 32; ++c) acc += x[c] * vw[o * 32 + c];
      Vp[(size_t)o * N] = (_Float16)acc;
    }
  } else {
    // ---- small Q projection at 32x32: 16 e per block ----
    const int qbid   = bid - KP_BLK - VP_BLK;
    const int pix    = (qbid >> 2) * 256 + threadIdx.x;   // 0..2047
    const int estart = (qbid & 3) * 16;
    const int b = pix >> 10, p10 = pix & 1023;

    const float* xb = xt + (size_t)b * 64 * 1024 + p10;
    float x[64];
#pragma unroll
    for (int c = 0; c < 64; ++c) x[c] = xb[(size_t)c * 1024];

    float* Qp = Qs + (size_t)pix * 64 + estart;
#pragma unroll 1
    for (int e0 = 0; e0 < 16; e0 += 4) {
      f32x4 v;
#pragma unroll
      for (int j = 0; j < 4; ++j) {
        const int e = estart + e0 + j;
        float acc = qb[e];
#pragma unroll
        for (int c = 0; c < 64; ++c) acc += x[c] * qw[e * 64 + c];
        v[j] = acc * SC;
      }
      *(f32x4*)(Qp + e0) = v;
    }
  }
}

// ---------------------------------------------------------------------------
// Kernel 2: bilinear 3x upsample of the PROJECTED field (conv commutes with
// bilinear interp). Thread = (output pixel, e-quarter). (identical to R9)
// ---------------------------------------------------------------------------
__global__ __launch_bounds__(256) void upsample_q_kernel(
    const float* __restrict__ Qs,   // [B*1024][64], SC-scaled
    _Float16* __restrict__ Q)       // [B][N][E]
{
  const int tid = blockIdx.x * 256 + threadIdx.x;
  const int p   = tid >> 2;
  const int eq  = tid & 3;
  const int b   = p / N, n = p % N;
  const int ho  = n / 96, wo = n % 96;

  const float sh = (ho + 0.5f) * (1.0f / 3.0f) - 0.5f;
  const float sw = (wo + 0.5f) * (1.0f / 3.0f) - 0.5f;
  int h0 = (int)floorf(sh); const float fh = sh - (float)h0;
  int w0 = (int)floorf(sw); const float fw = sw - (float)w0;
  int h1 = min(h0 + 1, 31); h0 = max(h0, 0);
  int w1 = min(w0 + 1, 31); w0 = max(w0, 0);

  const float c00 = (1.f - fh) * (1.f - fw), c01 = (1.f - fh) * fw;
  const float c10 = fh * (1.f - fw),         c11 = fh * fw;

  const float* Qb = Qs + (size_t)b * 1024 * 64 + eq * 16;
  const f32x4* q00 = (const f32x4*)(Qb + (h0 * 32 + w0) * 64);
  const f32x4* q01 = (const f32x4*)(Qb + (h0 * 32 + w1) * 64);
  const f32x4* q10 = (const f32x4*)(Qb + (h1 * 32 + w0) * 64);
  const f32x4* q11 = (const f32x4*)(Qb + (h1 * 32 + w1) * 64);

  union { _Float16 h[16]; uint4 v[2]; } pk;
#pragma unroll
  for (int j4 = 0; j4 < 4; ++j4) {
    const f32x4 a = q00[j4] * c00 + q01[j4] * c01 + q10[j4] * c10 + q11[j4] * c11;
#pragma unroll
    for (int i = 0; i < 4; ++i) pk.h[4 * j4 + i] = (_Float16)a[i];
  }

  _Float16* Qp = Q + (size_t)p * E + eq * 16;
  *(uint4*)(Qp)     = pk.v[0];
  *(uint4*)(Qp + 8) = pk.v[1];
}

// ---------------------------------------------------------------------------
// Kernel 3: flash attention partials (R7 body, templated SPLIT).
// 4 waves x 32 rows; K/V double-buffered in LDS (XOR-swizzled via
// pre-swizzled global source + linear global_load_lds dest + swizzled reads).
// Swapped QK^T; shuffle-free PV (k-slot permutation).
// ---------------------------------------------------------------------------
template<int SPLIT>
__global__ __launch_bounds__(256) void attn_kernel(
    const _Float16* __restrict__ Q,
    const _Float16* __restrict__ K,
    const _Float16* __restrict__ Vt,
    float* __restrict__ OutWS,   // [SPLIT][B][N][CO]
    float* __restrict__ SumWS)   // [SPLIT][B][N]
{
  constexpr int MCHUNK = N / SPLIT;
  constexpr int ROUNDS = MCHUNK / KVBLK;

  __shared__ _Float16 Kl[2][KVBLK][64];   // 16 KB: [buf][m_local][e]
  __shared__ _Float16 Vl[2][CO][KVBLK];   //  8 KB: [buf][o][m_local]

  const int tid  = threadIdx.x;
  const int wave = tid >> 6, lane = tid & 63;
  const int r16  = lane & 15, g = lane >> 4;

  const int work  = blockIdx.x;
  const int chunk = work & (SPLIT - 1);
  const int t128  = work / SPLIT;         // 0..143
  const int b     = t128 / 72;
  const int rowbase = (t128 % 72) * 128 + wave * 32;

  const _Float16* Qb = Q  + ((size_t)b * N + rowbase) * E;
  const _Float16* Kb = K  + (size_t)b * N * E;
  const _Float16* Vb = Vt + (size_t)b * CO * N;

  // staging lane mapping: lane -> (row-in-8-group, 16B chunk), swizzled source
  const int sub = lane >> 3, c8 = lane & 7;
  const int swz = 8 * (c8 ^ sub);          // halfs offset of swizzled 16B chunk

  const int mstart = chunk * MCHUNK;

  // Q B-fragments: 2 row-tiles x 2 k-steps (contiguous 16B per lane)
  f16x8 qf[2][2];
#pragma unroll
  for (int rt = 0; rt < 2; ++rt)
#pragma unroll
    for (int ks = 0; ks < 2; ++ks)
      qf[rt][ks] = *(const f16x8*)(Qb + (rt * 16 + r16) * E + ks * 32 + g * 8);

  // prologue: stage round 0 into buf 0 (each wave: 2 K-instrs + 1 V-instr)
  {
    const _Float16* gk = Kb + (size_t)(mstart + 16 * wave + sub) * E + swz;
    GLOAD16(gk,         &Kl[0][16 * wave][0]);
    GLOAD16(gk + 8 * E, &Kl[0][16 * wave + 8][0]);
    const _Float16* gv = Vb + (size_t)(8 * wave + sub) * N + mstart + swz;
    GLOAD16(gv,         &Vl[0][8 * wave][0]);
  }

  f32x4 oacc[2][2];
#pragma unroll
  for (int a = 0; a < 2; ++a)
#pragma unroll
    for (int c = 0; c < 2; ++c) oacc[a][c] = (f32x4){0.f, 0.f, 0.f, 0.f};
  float sume[2] = {0.f, 0.f};

  // swizzled LDS read offsets (lane-constant)
  const int rsw   = (r16 & 7) << 4;                      // row XOR key (bytes)
  const int kcol0 = ((0 * 64 + g * 16) ^ rsw) >> 1;      // ks=0, halfs
  const int kcol1 = ((1 * 64 + g * 16) ^ rsw) >> 1;      // ks=1

  __syncthreads();

  int cur = 0;
  for (int r = 0; r < ROUNDS; ++r) {
    // issue next round's staging (overlaps with compute below)
    if (r + 1 < ROUNDS) {
      const int m0 = mstart + (r + 1) * KVBLK;
      const _Float16* gk = Kb + (size_t)(m0 + 16 * wave + sub) * E + swz;
      GLOAD16(gk,         &Kl[cur ^ 1][16 * wave][0]);
      GLOAD16(gk + 8 * E, &Kl[cur ^ 1][16 * wave + 8][0]);
      const _Float16* gv = Vb + (size_t)(8 * wave + sub) * N + m0 + swz;
      GLOAD16(gv,         &Vl[cur ^ 1][8 * wave][0]);
    }

    // compute current buffer: 2 sub-iterations of 32 m
#pragma unroll
    for (int it = 0; it < 2; ++it) {
      f16x8 kf[2][2];
#pragma unroll
      for (int mt = 0; mt < 2; ++mt) {
        const int krow = it * 32 + mt * 16 + r16;
        kf[mt][0] = *(const f16x8*)&Kl[cur][krow][kcol0];
        kf[mt][1] = *(const f16x8*)&Kl[cur][krow][kcol1];
      }
      union { f16x4 h[2]; f16x8 v; } vf[2];
#pragma unroll
      for (int ot = 0; ot < 2; ++ot) {
        const int vrow = ot * 16 + r16;
        const int v0 = ((it * 64 + 8 * g) ^ rsw) >> 1;
        const int v1 = ((it * 64 + 32 + 8 * g) ^ rsw) >> 1;
        vf[ot].h[0] = *(const f16x4*)&Vl[cur][vrow][v0];
        vf[ot].h[1] = *(const f16x4*)&Vl[cur][vrow][v1];
      }

#pragma unroll
      for (int rt = 0; rt < 2; ++rt) {
        f32x4 s0 = (f32x4){0.f, 0.f, 0.f, 0.f};
        f32x4 s1 = (f32x4){0.f, 0.f, 0.f, 0.f};
        s0 = MFMA(kf[0][0], qf[rt][0], s0);
        s0 = MFMA(kf[0][1], qf[rt][1], s0);
        s1 = MFMA(kf[1][0], qf[rt][0], s1);
        s1 = MFMA(kf[1][1], qf[rt][1], s1);

        float p0[4], p1[4];
#pragma unroll
        for (int i = 0; i < 4; ++i) {
          p0[i] = __builtin_amdgcn_exp2f(s0[i]);   // SC pre-folded into Q
          p1[i] = __builtin_amdgcn_exp2f(s1[i]);
        }
        sume[rt] += p0[0] + p0[1] + p0[2] + p0[3]
                  + p1[0] + p1[1] + p1[2] + p1[3];

        // PV B-frag: lane's own values, permuted-k order (NO shuffles).
        union { unsigned u[4]; f16x8 v; } pb;
        pb.u[0] = __builtin_bit_cast(unsigned, __builtin_amdgcn_cvt_pkrtz(p0[0], p0[1]));
        pb.u[1] = __builtin_bit_cast(unsigned, __builtin_amdgcn_cvt_pkrtz(p0[2], p0[3]));
        pb.u[2] = __builtin_bit_cast(unsigned, __builtin_amdgcn_cvt_pkrtz(p1[0], p1[1]));
        pb.u[3] = __builtin_bit_cast(unsigned, __builtin_amdgcn_cvt_pkrtz(p1[2], p1[3]));

        oacc[rt][0] = MFMA(vf[0].v, pb.v, oacc[rt][0]);
        oacc[rt][1] = MFMA(vf[1].v, pb.v, oacc[rt][1]);
      }
    }

    __syncthreads();   // drains vmcnt (staging done) + all waves past cur
    cur ^= 1;
  }

  // reduce sumexp across the four 16-lane groups (each held different m)
#pragma unroll
  for (int rt = 0; rt < 2; ++rt) {
    sume[rt] += __shfl_xor(sume[rt], 16);
    sume[rt] += __shfl_xor(sume[rt], 32);
  }

  float* OW = OutWS + (size_t)(chunk * B + b) * N * CO;
  float* SW = SumWS + (size_t)(chunk * B + b) * N;
#pragma unroll
  for (int rt = 0; rt < 2; ++rt) {
    const int n = rowbase + rt * 16 + r16;
    if (g == 0) SW[n] = sume[rt];
#pragma unroll
    for (int ot = 0; ot < 2; ++ot)
#pragma unroll
      for (int i = 0; i < 4; ++i)
        OW[(size_t)n * CO + ot * 16 + 4 * g + i] = oacc[rt][ot][i];
  }
}

// ---------------------------------------------------------------------------
// Kernel 4: combine split-m partials, normalize, out_w conv, BN, ReLU.
// Block: 64 pixels x 4 split-groups, dense float4 reads, LDS reduce.
// ---------------------------------------------------------------------------
template<int SPLIT>
__global__ __launch_bounds__(256) void epi_kernel(
    const float* __restrict__ OutWS, const float* __restrict__ SumWS,
    const float* __restrict__ ow, const float* __restrict__ gamma,
    const float* __restrict__ beta, const float* __restrict__ mean,
    const float* __restrict__ var, float* __restrict__ out)
{
  __shared__ float part[4][64][33];
  __shared__ float psum[4][64];

  const int tid  = threadIdx.x;
  const int nloc = tid & 63, grp = tid >> 6;
  const int pix  = blockIdx.x * 64 + nloc;
  const int b    = pix / N, n = pix % N;

  f32x4 acc[8];
#pragma unroll
  for (int j = 0; j < 8; ++j) acc[j] = (f32x4){0.f, 0.f, 0.f, 0.f};
  float ssum = 0.f;
#pragma unroll
  for (int k = 0; k < SPLIT / 4; ++k) {
    const int sc = grp * (SPLIT / 4) + k;
    const f32x4* src = (const f32x4*)(OutWS + ((size_t)(sc * B + b) * N + n) * CO);
#pragma unroll
    for (int j = 0; j < 8; ++j) acc[j] += src[j];
    ssum += SumWS[(size_t)(sc * B + b) * N + n];
  }
#pragma unroll
  for (int j = 0; j < 8; ++j)
#pragma unroll
    for (int i = 0; i < 4; ++i)
      part[grp][nloc][j * 4 + i] = acc[j][i];
  psum[grp][nloc] = ssum;
  __syncthreads();

  const float s = psum[0][nloc] + psum[1][nloc] + psum[2][nloc] + psum[3][nloc];
  const float inv = 1.f / s;
  float onr[CO];
#pragma unroll
  for (int o = 0; o < CO; ++o)
    onr[o] = (part[0][nloc][o] + part[1][nloc][o] +
              part[2][nloc][o] + part[3][nloc][o]) * inv;

#pragma unroll
  for (int i = 0; i < 16; ++i) {
    const int t = grp + 4 * i;
    float acc2 = 0.f;
#pragma unroll
    for (int o = 0; o < CO; ++o) acc2 += onr[o] * ow[t * CO + o];
    const float scl = gamma[t] * rsqrtf(var[t] + 1e-5f);
    const float bia = beta[t] - mean[t] * scl;
    const float gv  = acc2 * scl + bia;
    out[(size_t)(b * CT + t) * N + n] = fmaxf(gv, 0.f);
  }
}

// ---------------------------------------------------------------------------
extern "C" void kernel_launch(void* const* d_in, const int* in_sizes, int n_in,
                              void* d_out, int out_size, void* d_ws, size_t ws_size,
                              hipStream_t stream) {
  const float* xt = (const float*)d_in[0];
  const float* xo = (const float*)d_in[1];
  const float* qw = (const float*)d_in[2];
  const float* qb = (const float*)d_in[3];
  const float* kw = (const float*)d_in[4];
  const float* kb = (const float*)d_in[5];
  const float* vw = (const float*)d_in[6];
  const float* vb = (const float*)d_in[7];
  const float* ow = (const float*)d_in[8];
  const float* gm = (const float*)d_in[9];
  const float* bt = (const float*)d_in[10];
  const float* mn = (const float*)d_in[11];
  const float* vr = (const float*)d_in[12];

  char* ws = (char*)d_ws;
  _Float16* Qd  = (_Float16*)ws;  ws += (size_t)B * N * E * 2;    // 2.36 MB
  _Float16* Kd  = (_Float16*)ws;  ws += (size_t)B * N * E * 2;    // 2.36 MB
  _Float16* Vtd = (_Float16*)ws;  ws += (size_t)B * CO * N * 2;   // 1.18 MB
  float* Qs     = (float*)ws;     ws += (size_t)B * 1024 * 64 * 4;// 0.52 MB
  float* OutWS  = (float*)ws;     // SPLIT*B*N*CO*4 (+SumWS)
  const size_t base   = (size_t)(ws - (char*)d_ws);
  const size_t need16 = base + (size_t)16 * B * N * (CO + 1) * 4; // ~45.4 MB

  proj_fused_kernel<<<KP_BLK + VP_BLK + QP_BLK, 256, 0, stream>>>(
      xo, kw, kb, vw, vb, Kd, Vtd, xt, qw, qb, Qs);
  upsample_q_kernel<<<(B * N * 4) / 256, 256, 0, stream>>>(Qs, Qd);

  if (ws_size >= need16) {
    float* SumWS = OutWS + (size_t)16 * B * N * CO;
    attn_kernel<16><<<(N / 128) * B * 16, 256, 0, stream>>>(Qd, Kd, Vtd, OutWS, SumWS);
    epi_kernel<16><<<(B * N) / 64, 256, 0, stream>>>(OutWS, SumWS, ow, gm, bt, mn, vr,
                                                     (float*)d_out);
  } else {
    float* SumWS = OutWS + (size_t)8 * B * N * CO;
    attn_kernel<8><<<(N / 128) * B * 8, 256, 0, stream>>>(Qd, Kd, Vtd, OutWS, SumWS);
    epi_kernel<8><<<(B * N) / 64, 256, 0, stream>>>(OutWS, SumWS, ow, gm, bt, mn, vr,
                                                    (float*)d_out);
  }
}

// Round 11
// 158.751 us; speedup vs baseline: 2.7809x; 1.0813x over previous
//
#include <hip/hip_runtime.h>
#include <hip/hip_bf16.h>

// ---------------------------------------------------------------------------
// CrossAttentionBlock: bilinear 3x upsample -> QKV 1x1 projections ->
// full cross-attention (N=9216, E=64, Co=32) -> 1x1 conv + BN + ReLU.
// Flash-style, fp16 MFMA 16x16x32, fp32 accumulate, no-max softmax
// (scores bounded), split-m partials combined additively in epilogue.
//
// R11 vs R10 (171.7us; attn 55.3us VALU/trans-bound: VALUBusy 56% vs
// MfmaUtil 23%; ~75MB f32 partial round-trip):
//  - attn: sum-of-exp via ones-MFMA (sacc = MFMA(ones, P, sacc)) -> kills
//    16 v_add/it + epilogue shfl_xor reduce; moves work to MFMA pipe.
//  - attn/epi: OutWS partials in fp16 (packed cvt_pkrtz stores) -> attn
//    WRITE 38->19.5MB, epi FETCH 37.7->18.9MB. Error ~1e-5 (analyzed).
//  - proj_fused / upsample_q byte-identical to R10.
// ---------------------------------------------------------------------------

constexpr int B   = 2;
constexpr int N   = 9216;   // 96*96
constexpr int E   = 64;
constexpr int CO  = 32;
constexpr int CT  = 64;
constexpr int KVBLK = 64;

constexpr int KP_BLK = 288;  // K proj: 72 px-blocks x 4 e-groups
constexpr int VP_BLK = 288;  // V proj: 72 px-blocks x 4 o-groups
constexpr int QP_BLK = 32;   // Qs proj: 8 px-blocks x 4 e-groups

typedef _Float16 f16x8 __attribute__((ext_vector_type(8)));
typedef _Float16 f16x4 __attribute__((ext_vector_type(4)));
typedef float    f32x4 __attribute__((ext_vector_type(4)));
typedef unsigned int u32;

#define MFMA(a, b, c) __builtin_amdgcn_mfma_f32_16x16x32_f16((a), (b), (c), 0, 0, 0)

// async global->LDS, 16B per lane, dest = base + lane*16 (wave-linear)
#define GLOAD16(gsrc, ldst)                                                     \
  __builtin_amdgcn_global_load_lds(                                             \
      (const __attribute__((address_space(1))) u32*)(gsrc),                     \
      (__attribute__((address_space(3))) u32*)(ldst), 16, 0, 0)

// exp(s/8) == exp2(s * SC); SC folded into the small Q projection.
#define SC 0.18033688011112042f

// ---------------------------------------------------------------------------
// Kernel 1 (fused projections, block-range split, block-uniform channels):
//  [0,288):   K proj  — block = (72 px-blk) x (4 e-groups of 16)
//  [288,576): V proj  — block = (72 px-blk) x (4 o-groups of 8)
//  [576,608): Qs proj — block = (8 px-blk)  x (4 e-groups of 16)
// ---------------------------------------------------------------------------
__global__ __launch_bounds__(256) void proj_fused_kernel(
    const float* __restrict__ xo,   // [B][32][N]
    const float* __restrict__ kw, const float* __restrict__ kb,
    const float* __restrict__ vw, const float* __restrict__ vb,
    _Float16* __restrict__ K, _Float16* __restrict__ Vt,
    const float* __restrict__ xt,   // [B][64][32][32]
    const float* __restrict__ qw, const float* __restrict__ qb,
    float* __restrict__ Qs)         // [B*1024][64], SC-scaled
{
  const int bid = blockIdx.x;
  if (bid < KP_BLK) {
    // ---- K projection: 16 e per block (block-uniform e-range) ----
    const int p      = (bid >> 2) * 256 + threadIdx.x;
    const int estart = (bid & 3) * 16;
    const int b = p / N, n = p % N;

    const float* xb = xo + (size_t)b * CO * N + n;
    float x[32];
#pragma unroll
    for (int c = 0; c < 32; ++c) x[c] = xb[(size_t)c * N];

    _Float16* Kp = K + (size_t)p * E + estart;
#pragma unroll 1
    for (int e0 = 0; e0 < 16; e0 += 8) {
      union { _Float16 h[8]; uint4 v; } pk;
#pragma unroll
      for (int j = 0; j < 8; ++j) {
        const int e = estart + e0 + j;
        float acc = kb[e];
#pragma unroll
        for (int c = 0; c < 32; ++c) acc += x[c] * kw[e * 32 + c];
        pk.h[j] = (_Float16)acc;
      }
      *(uint4*)(Kp + e0) = pk.v;
    }
  } else if (bid < KP_BLK + VP_BLK) {
    // ---- V projection: 8 o per block (block-uniform o-range) ----
    const int vbid   = bid - KP_BLK;
    const int p      = (vbid >> 2) * 256 + threadIdx.x;
    const int ostart = (vbid & 3) * 8;
    const int b = p / N, n = p % N;

    const float* xb = xo + (size_t)b * CO * N + n;
    float x[32];
#pragma unroll
    for (int c = 0; c < 32; ++c) x[c] = xb[(size_t)c * N];

    _Float16* Vp = Vt + (size_t)b * CO * N + n;
#pragma unroll 1
    for (int j = 0; j < 8; ++j) {
      const int o = ostart + j;
      float acc = vb[o];
#pragma unroll
      for (int c = 0; c < 32; ++c) acc += x[c] * vw[o * 32 + c];
      Vp[(size_t)o * N] = (_Float16)acc;
    }
  } else {
    // ---- small Q projection at 32x32: 16 e per block ----
    const int qbid   = bid - KP_BLK - VP_BLK;
    const int pix    = (qbid >> 2) * 256 + threadIdx.x;   // 0..2047
    const int estart = (qbid & 3) * 16;
    const int b = pix >> 10, p10 = pix & 1023;

    const float* xb = xt + (size_t)b * 64 * 1024 + p10;
    float x[64];
#pragma unroll
    for (int c = 0; c < 64; ++c) x[c] = xb[(size_t)c * 1024];

    float* Qp = Qs + (size_t)pix * 64 + estart;
#pragma unroll 1
    for (int e0 = 0; e0 < 16; e0 += 4) {
      f32x4 v;
#pragma unroll
      for (int j = 0; j < 4; ++j) {
        const int e = estart + e0 + j;
        float acc = qb[e];
#pragma unroll
        for (int c = 0; c < 64; ++c) acc += x[c] * qw[e * 64 + c];
        v[j] = acc * SC;
      }
      *(f32x4*)(Qp + e0) = v;
    }
  }
}

// ---------------------------------------------------------------------------
// Kernel 2: bilinear 3x upsample of the PROJECTED field (conv commutes with
// bilinear interp). Thread = (output pixel, e-quarter). (identical to R10)
// ---------------------------------------------------------------------------
__global__ __launch_bounds__(256) void upsample_q_kernel(
    const float* __restrict__ Qs,   // [B*1024][64], SC-scaled
    _Float16* __restrict__ Q)       // [B][N][E]
{
  const int tid = blockIdx.x * 256 + threadIdx.x;
  const int p   = tid >> 2;
  const int eq  = tid & 3;
  const int b   = p / N, n = p % N;
  const int ho  = n / 96, wo = n % 96;

  const float sh = (ho + 0.5f) * (1.0f / 3.0f) - 0.5f;
  const float sw = (wo + 0.5f) * (1.0f / 3.0f) - 0.5f;
  int h0 = (int)floorf(sh); const float fh = sh - (float)h0;
  int w0 = (int)floorf(sw); const float fw = sw - (float)w0;
  int h1 = min(h0 + 1, 31); h0 = max(h0, 0);
  int w1 = min(w0 + 1, 31); w0 = max(w0, 0);

  const float c00 = (1.f - fh) * (1.f - fw), c01 = (1.f - fh) * fw;
  const float c10 = fh * (1.f - fw),         c11 = fh * fw;

  const float* Qb = Qs + (size_t)b * 1024 * 64 + eq * 16;
  const f32x4* q00 = (const f32x4*)(Qb + (h0 * 32 + w0) * 64);
  const f32x4* q01 = (const f32x4*)(Qb + (h0 * 32 + w1) * 64);
  const f32x4* q10 = (const f32x4*)(Qb + (h1 * 32 + w0) * 64);
  const f32x4* q11 = (const f32x4*)(Qb + (h1 * 32 + w1) * 64);

  union { _Float16 h[16]; uint4 v[2]; } pk;
#pragma unroll
  for (int j4 = 0; j4 < 4; ++j4) {
    const f32x4 a = q00[j4] * c00 + q01[j4] * c01 + q10[j4] * c10 + q11[j4] * c11;
#pragma unroll
    for (int i = 0; i < 4; ++i) pk.h[4 * j4 + i] = (_Float16)a[i];
  }

  _Float16* Qp = Q + (size_t)p * E + eq * 16;
  *(uint4*)(Qp)     = pk.v[0];
  *(uint4*)(Qp + 8) = pk.v[1];
}

// ---------------------------------------------------------------------------
// Kernel 3: flash attention partials (templated SPLIT).
// 4 waves x 32 rows; K/V double-buffered in LDS (XOR-swizzled via
// pre-swizzled global source + linear global_load_lds dest + swizzled reads).
// Swapped QK^T; shuffle-free PV (k-slot permutation).
// R11: sum-of-exp via ones-MFMA (no shfl reduce); fp16 packed partial stores.
// ---------------------------------------------------------------------------
template<int SPLIT>
__global__ __launch_bounds__(256) void attn_kernel(
    const _Float16* __restrict__ Q,
    const _Float16* __restrict__ K,
    const _Float16* __restrict__ Vt,
    _Float16* __restrict__ OutWS,   // [SPLIT][B][N][CO] fp16
    float* __restrict__ SumWS)      // [SPLIT][B][N] f32
{
  constexpr int MCHUNK = N / SPLIT;
  constexpr int ROUNDS = MCHUNK / KVBLK;

  __shared__ _Float16 Kl[2][KVBLK][64];   // 16 KB: [buf][m_local][e]
  __shared__ _Float16 Vl[2][CO][KVBLK];   //  8 KB: [buf][o][m_local]

  const int tid  = threadIdx.x;
  const int wave = tid >> 6, lane = tid & 63;
  const int r16  = lane & 15, g = lane >> 4;

  const int work  = blockIdx.x;
  const int chunk = work & (SPLIT - 1);
  const int t128  = work / SPLIT;         // 0..143
  const int b     = t128 / 72;
  const int rowbase = (t128 % 72) * 128 + wave * 32;

  const _Float16* Qb = Q  + ((size_t)b * N + rowbase) * E;
  const _Float16* Kb = K  + (size_t)b * N * E;
  const _Float16* Vb = Vt + (size_t)b * CO * N;

  // staging lane mapping: lane -> (row-in-8-group, 16B chunk), swizzled source
  const int sub = lane >> 3, c8 = lane & 7;
  const int swz = 8 * (c8 ^ sub);          // halfs offset of swizzled 16B chunk

  const int mstart = chunk * MCHUNK;

  // Q B-fragments: 2 row-tiles x 2 k-steps (contiguous 16B per lane)
  f16x8 qf[2][2];
#pragma unroll
  for (int rt = 0; rt < 2; ++rt)
#pragma unroll
    for (int ks = 0; ks < 2; ++ks)
      qf[rt][ks] = *(const f16x8*)(Qb + (rt * 16 + r16) * E + ks * 32 + g * 8);

  // ones A-fragment for the sum-of-exp MFMA
  f16x8 onesf;
#pragma unroll
  for (int i = 0; i < 8; ++i) onesf[i] = (_Float16)1.0f;

  // prologue: stage round 0 into buf 0 (each wave: 2 K-instrs + 1 V-instr)
  {
    const _Float16* gk = Kb + (size_t)(mstart + 16 * wave + sub) * E + swz;
    GLOAD16(gk,         &Kl[0][16 * wave][0]);
    GLOAD16(gk + 8 * E, &Kl[0][16 * wave + 8][0]);
    const _Float16* gv = Vb + (size_t)(8 * wave + sub) * N + mstart + swz;
    GLOAD16(gv,         &Vl[0][8 * wave][0]);
  }

  f32x4 oacc[2][2];
#pragma unroll
  for (int a = 0; a < 2; ++a)
#pragma unroll
    for (int c = 0; c < 2; ++c) oacc[a][c] = (f32x4){0.f, 0.f, 0.f, 0.f};
  f32x4 sacc[2];
  sacc[0] = (f32x4){0.f, 0.f, 0.f, 0.f};
  sacc[1] = (f32x4){0.f, 0.f, 0.f, 0.f};

  // swizzled LDS read offsets (lane-constant)
  const int rsw   = (r16 & 7) << 4;                      // row XOR key (bytes)
  const int kcol0 = ((0 * 64 + g * 16) ^ rsw) >> 1;      // ks=0, halfs
  const int kcol1 = ((1 * 64 + g * 16) ^ rsw) >> 1;      // ks=1

  __syncthreads();

  int cur = 0;
  for (int r = 0; r < ROUNDS; ++r) {
    // issue next round's staging (overlaps with compute below)
    if (r + 1 < ROUNDS) {
      const int m0 = mstart + (r + 1) * KVBLK;
      const _Float16* gk = Kb + (size_t)(m0 + 16 * wave + sub) * E + swz;
      GLOAD16(gk,         &Kl[cur ^ 1][16 * wave][0]);
      GLOAD16(gk + 8 * E, &Kl[cur ^ 1][16 * wave + 8][0]);
      const _Float16* gv = Vb + (size_t)(8 * wave + sub) * N + m0 + swz;
      GLOAD16(gv,         &Vl[cur ^ 1][8 * wave][0]);
    }

    // compute current buffer: 2 sub-iterations of 32 m
#pragma unroll
    for (int it = 0; it < 2; ++it) {
      f16x8 kf[2][2];
#pragma unroll
      for (int mt = 0; mt < 2; ++mt) {
        const int krow = it * 32 + mt * 16 + r16;
        kf[mt][0] = *(const f16x8*)&Kl[cur][krow][kcol0];
        kf[mt][1] = *(const f16x8*)&Kl[cur][krow][kcol1];
      }
      union { f16x4 h[2]; f16x8 v; } vf[2];
#pragma unroll
      for (int ot = 0; ot < 2; ++ot) {
        const int vrow = ot * 16 + r16;
        const int v0 = ((it * 64 + 8 * g) ^ rsw) >> 1;
        const int v1 = ((it * 64 + 32 + 8 * g) ^ rsw) >> 1;
        vf[ot].h[0] = *(const f16x4*)&Vl[cur][vrow][v0];
        vf[ot].h[1] = *(const f16x4*)&Vl[cur][vrow][v1];
      }

#pragma unroll
      for (int rt = 0; rt < 2; ++rt) {
        f32x4 s0 = (f32x4){0.f, 0.f, 0.f, 0.f};
        f32x4 s1 = (f32x4){0.f, 0.f, 0.f, 0.f};
        s0 = MFMA(kf[0][0], qf[rt][0], s0);
        s0 = MFMA(kf[0][1], qf[rt][1], s0);
        s1 = MFMA(kf[1][0], qf[rt][0], s1);
        s1 = MFMA(kf[1][1], qf[rt][1], s1);

        float p0[4], p1[4];
#pragma unroll
        for (int i = 0; i < 4; ++i) {
          p0[i] = __builtin_amdgcn_exp2f(s0[i]);   // SC pre-folded into Q
          p1[i] = __builtin_amdgcn_exp2f(s1[i]);
        }

        // PV B-frag: lane's own values, permuted-k order (NO shuffles).
        union { unsigned u[4]; f16x8 v; } pb;
        pb.u[0] = __builtin_bit_cast(unsigned, __builtin_amdgcn_cvt_pkrtz(p0[0], p0[1]));
        pb.u[1] = __builtin_bit_cast(unsigned, __builtin_amdgcn_cvt_pkrtz(p0[2], p0[3]));
        pb.u[2] = __builtin_bit_cast(unsigned, __builtin_amdgcn_cvt_pkrtz(p1[0], p1[1]));
        pb.u[3] = __builtin_bit_cast(unsigned, __builtin_amdgcn_cvt_pkrtz(p1[2], p1[3]));

        oacc[rt][0] = MFMA(vf[0].v, pb.v, oacc[rt][0]);
        oacc[rt][1] = MFMA(vf[1].v, pb.v, oacc[rt][1]);
        // sum-of-exp: ones x P -> every lane gets full column sum over k
        sacc[rt]    = MFMA(onesf,   pb.v, sacc[rt]);
      }
    }

    __syncthreads();   // drains vmcnt (staging done) + all waves past cur
    cur ^= 1;
  }

  _Float16* OW = OutWS + (size_t)(chunk * B + b) * N * CO;
  float*    SW = SumWS + (size_t)(chunk * B + b) * N;
#pragma unroll
  for (int rt = 0; rt < 2; ++rt) {
    const int n = rowbase + rt * 16 + r16;
    if (g == 0) SW[n] = sacc[rt][0];   // all sacc elems equal (ones rows)
#pragma unroll
    for (int ot = 0; ot < 2; ++ot) {
      uint2 pko;
      pko.x = __builtin_bit_cast(unsigned,
                __builtin_amdgcn_cvt_pkrtz(oacc[rt][ot][0], oacc[rt][ot][1]));
      pko.y = __builtin_bit_cast(unsigned,
                __builtin_amdgcn_cvt_pkrtz(oacc[rt][ot][2], oacc[rt][ot][3]));
      *(uint2*)(OW + (size_t)n * CO + ot * 16 + 4 * g) = pko;
    }
  }
}

// ---------------------------------------------------------------------------
// Kernel 4: combine split-m partials (fp16), normalize, out_w conv, BN, ReLU.
// Block: 64 pixels x 4 split-groups, f16x8 reads, LDS reduce.
// ---------------------------------------------------------------------------
template<int SPLIT>
__global__ __launch_bounds__(256) void epi_kernel(
    const _Float16* __restrict__ OutWS, const float* __restrict__ SumWS,
    const float* __restrict__ ow, const float* __restrict__ gamma,
    const float* __restrict__ beta, const float* __restrict__ mean,
    const float* __restrict__ var, float* __restrict__ out)
{
  __shared__ float part[4][64][33];
  __shared__ float psum[4][64];

  const int tid  = threadIdx.x;
  const int nloc = tid & 63, grp = tid >> 6;
  const int pix  = blockIdx.x * 64 + nloc;
  const int b    = pix / N, n = pix % N;

  float accf[32];
#pragma unroll
  for (int j = 0; j < 32; ++j) accf[j] = 0.f;
  float ssum = 0.f;
#pragma unroll
  for (int k = 0; k < SPLIT / 4; ++k) {
    const int sc = grp * (SPLIT / 4) + k;
    const f16x8* src = (const f16x8*)(OutWS + ((size_t)(sc * B + b) * N + n) * CO);
#pragma unroll
    for (int j = 0; j < 4; ++j) {
      const f16x8 c = src[j];
#pragma unroll
      for (int i = 0; i < 8; ++i) accf[j * 8 + i] += (float)c[i];
    }
    ssum += SumWS[(size_t)(sc * B + b) * N + n];
  }
#pragma unroll
  for (int j = 0; j < 32; ++j) part[grp][nloc][j] = accf[j];
  psum[grp][nloc] = ssum;
  __syncthreads();

  const float s = psum[0][nloc] + psum[1][nloc] + psum[2][nloc] + psum[3][nloc];
  const float inv = 1.f / s;
  float onr[CO];
#pragma unroll
  for (int o = 0; o < CO; ++o)
    onr[o] = (part[0][nloc][o] + part[1][nloc][o] +
              part[2][nloc][o] + part[3][nloc][o]) * inv;

#pragma unroll
  for (int i = 0; i < 16; ++i) {
    const int t = grp + 4 * i;
    float acc2 = 0.f;
#pragma unroll
    for (int o = 0; o < CO; ++o) acc2 += onr[o] * ow[t * CO + o];
    const float scl = gamma[t] * rsqrtf(var[t] + 1e-5f);
    const float bia = beta[t] - mean[t] * scl;
    const float gv  = acc2 * scl + bia;
    out[(size_t)(b * CT + t) * N + n] = fmaxf(gv, 0.f);
  }
}

// ---------------------------------------------------------------------------
extern "C" void kernel_launch(void* const* d_in, const int* in_sizes, int n_in,
                              void* d_out, int out_size, void* d_ws, size_t ws_size,
                              hipStream_t stream) {
  const float* xt = (const float*)d_in[0];
  const float* xo = (const float*)d_in[1];
  const float* qw = (const float*)d_in[2];
  const float* qb = (const float*)d_in[3];
  const float* kw = (const float*)d_in[4];
  const float* kb = (const float*)d_in[5];
  const float* vw = (const float*)d_in[6];
  const float* vb = (const float*)d_in[7];
  const float* ow = (const float*)d_in[8];
  const float* gm = (const float*)d_in[9];
  const float* bt = (const float*)d_in[10];
  const float* mn = (const float*)d_in[11];
  const float* vr = (const float*)d_in[12];

  char* ws = (char*)d_ws;
  _Float16* Qd  = (_Float16*)ws;  ws += (size_t)B * N * E * 2;    // 2.36 MB
  _Float16* Kd  = (_Float16*)ws;  ws += (size_t)B * N * E * 2;    // 2.36 MB
  _Float16* Vtd = (_Float16*)ws;  ws += (size_t)B * CO * N * 2;   // 1.18 MB
  float* Qs     = (float*)ws;     ws += (size_t)B * 1024 * 64 * 4;// 0.52 MB
  _Float16* OutWS = (_Float16*)ws;  // SPLIT*B*N*CO*2 (+SumWS f32)
  const size_t base   = (size_t)(ws - (char*)d_ws);
  const size_t need16 = base + (size_t)16 * B * N * (CO * 2 + 4); // ~26.6 MB

  proj_fused_kernel<<<KP_BLK + VP_BLK + QP_BLK, 256, 0, stream>>>(
      xo, kw, kb, vw, vb, Kd, Vtd, xt, qw, qb, Qs);
  upsample_q_kernel<<<(B * N * 4) / 256, 256, 0, stream>>>(Qs, Qd);

  if (ws_size >= need16) {
    float* SumWS = (float*)(OutWS + (size_t)16 * B * N * CO);
    attn_kernel<16><<<(N / 128) * B * 16, 256, 0, stream>>>(Qd, Kd, Vtd, OutWS, SumWS);
    epi_kernel<16><<<(B * N) / 64, 256, 0, stream>>>(OutWS, SumWS, ow, gm, bt, mn, vr,
                                                     (float*)d_out);
  } else {
    float* SumWS = (float*)(OutWS + (size_t)8 * B * N * CO);
    attn_kernel<8><<<(N / 128) * B * 8, 256, 0, stream>>>(Qd, Kd, Vtd, OutWS, SumWS);
    epi_kernel<8><<<(B * N) / 64, 256, 0, stream>>>(OutWS, SumWS, ow, gm, bt, mn, vr,
                                                    (float*)d_out);
  }
}